// Round 9
// baseline (84.068 us; speedup 1.0000x reference)
//
#include <hip/hip_runtime.h>
#include <hip/hip_fp16.h>
#include <cmath>

#define BB 4
#define HH 64
#define WW 64

// ---- LDS pool, word offsets. POOL = 19669 w = 78676 B -> 2 blocks/CU ----
#define TFH   11520            // half-index: t_f [64][34] fp16 (words 5760..9024 region)
#define TCH   13696            // half-index: t_c
#define TMH   15872            // half-index: t_m
#define SLOT  9024             // words: [32 px][53 n] x 4 w  {ox,oy,-,-} -> packed taps
#define SBW   15808            // words: [53][33] scores (row 52 = sparsity)
#define AGG   17557            // words: [64][33] aggregate
#define POOLW 19669
#define PCB   0                // words: pc out [64][33], overlays dead window
#define HB    2112             // words: h1     [64][33], overlays dead window

typedef _Float16 half2v __attribute__((ext_vector_type(2)));
__device__ inline float fdot2u(uint32_t a, uint32_t b, float c) {
    return __builtin_amdgcn_fdot2(__builtin_bit_cast(half2v, a),
                                  __builtin_bit_cast(half2v, b), c, false);
}

// ---------------- NCHW -> NHWC fp16 transpose (LDS tiled) ----------------
__global__ __launch_bounds__(256) void transpose_half(const float* __restrict__ x,
                                                      __half* __restrict__ xth) {
    int bid = blockIdx.x;
    int b = bid >> 6, y = bid & 63;
    __shared__ float tile[64][65];
    const float* xp = x + ((size_t)b * 64 * HH + y) * WW;
    #pragma unroll
    for (int k = 0; k < 16; ++k) {
        int idx = threadIdx.x + (k << 8);
        int c = idx >> 6, w = idx & 63;
        tile[c][w] = xp[(size_t)c * HH * WW + w];
    }
    __syncthreads();
    __half* op = xth + ((size_t)(b * HH + y) * WW) * 64;
    #pragma unroll
    for (int k = 0; k < 16; ++k) {
        int idx = threadIdx.x + (k << 8);
        int w = idx >> 6, c = idx & 63;
        op[(size_t)w * 64 + c] = __float2half(tile[c][w]);
    }
}

// ---------------- fused main: 1 block (8 waves, 512 thr) per HALF row; 2 blocks/CU ----------------
__global__ __launch_bounds__(512, 4) void crossd_main(
    const __half* __restrict__ xth, const float* __restrict__ x,
    const float* __restrict__ p_n,
    const float* __restrict__ dwf_w, const float* __restrict__ dwf_b,
    const float* __restrict__ pwf_w, const float* __restrict__ pwf_b,
    const float* __restrict__ dwc_w, const float* __restrict__ dwc_b,
    const float* __restrict__ pwc_w, const float* __restrict__ pwc_b,
    const float* __restrict__ dwm_w, const float* __restrict__ dwm_b,
    const float* __restrict__ pwm_w, const float* __restrict__ pwm_b,
    const float* __restrict__ pc_w, const float* __restrict__ pc_b,
    const float* __restrict__ w1, const float* __restrict__ b1,
    const float* __restrict__ w2, const float* __restrict__ b2,
    float* __restrict__ out)
{
    __shared__ float P[POOLW];
    uint32_t* PU = reinterpret_cast<uint32_t*>(P);
    __half*   PH = reinterpret_cast<__half*>(P);
    const int tid  = threadIdx.x;
    const int lane = tid & 63;
    const int wv   = __builtin_amdgcn_readfirstlane(tid >> 6);   // 0..7
    const int pxl  = lane & 31;                                  // local pixel for GEMMs
    const int bid  = blockIdx.x;                                 // 512 blocks
    const int xh = bid & 1, y = (bid >> 1) & 63, b = bid >> 7;
    const int x0 = xh << 5;                                      // half-row origin
    const int ry0 = min(max(y - 1, 0), 59);                      // window rows ry0..ry0+4
    const __half* xbh = xth + (size_t)b * (HH * WW * 64);
    const uint2* xb2 = reinterpret_cast<const uint2*>(xbh);

    // ---- phase 0: stage 5-row x 36-col fp16 window into LDS ----
    {
        uint2* WINu = reinterpret_cast<uint2*>(P);
        for (int idx = tid; idx < 5 * 36 * 16; idx += 512) {
            int j = idx / 576;
            int rem = idx - j * 576;
            int col = rem >> 4, c4v = idx & 15;
            int gcol = min(max(x0 - 1 + col, 0), 63);
            WINu[(j * 36 + col) * 16 + c4v] = xb2[(((ry0 + j) << 6) + gcol) * 16 + c4v];
        }
    }
    __syncthreads();   // B0

    // ---- depthwise 3x3 from window: wave = 4 px, lane = ch; fp16 t-buffers ----
    {
        const int c = lane;
        float wf9[9], wc9[9], wm9[9];
        #pragma unroll
        for (int k9 = 0; k9 < 9; ++k9) {
            wf9[k9] = dwf_w[c * 9 + k9];
            wc9[k9] = dwc_w[c * 9 + k9];
            wm9[k9] = dwm_w[c * 9 + k9];
        }
        const float bf = dwf_b[c], bc = dwc_b[c], bm = dwm_b[c];
        #pragma unroll
        for (int i = 0; i < 4; ++i) {
            const int pl = wv * 4 + i;          // local px 0..31
            const int pg = x0 + pl;             // global px
            float af = bf, ac = bc, am = bm;
            #pragma unroll
            for (int dy = 0; dy < 3; ++dy) {
                int yy = y + dy - 1;
                if (yy < 0 || yy >= HH) continue;
                int j = yy - ry0;
                #pragma unroll
                for (int dx = 0; dx < 3; ++dx) {
                    int xx = pg + dx - 1;
                    if (xx < 0 || xx >= WW) continue;
                    int co = xx - x0 + 1;       // window col 0..33
                    float v = __half2float(PH[(j * 36 + co) * 64 + c]);
                    int k = dy * 3 + dx;
                    af = fmaf(v, wf9[k], af);
                    ac = fmaf(v, wc9[k], ac);
                    am = fmaf(v, wm9[k], am);
                }
            }
            PH[TFH + c * 34 + pl] = __float2half(af);
            PH[TCH + c * 34 + pl] = __float2half(ac);
            PH[TMH + c * 34 + pl] = __float2half(am);
        }
    }
    __syncthreads();   // B1

    // ---- fused f+c+m pointwise: lane = px (32 active), rows wave-uniform -> scalar weights ----
    {
        const int f0 = wv * 4, c0 = wv * 9, m0 = wv * 7;
        int ocM[7];
        float accF[4], accC[9], accM[7];
        #pragma unroll
        for (int r = 0; r < 4; ++r) accF[r] = pwf_b[f0 + r];
        #pragma unroll
        for (int r = 0; r < 9; ++r) accC[r] = pwc_b[c0 + r];
        #pragma unroll
        for (int r = 0; r < 7; ++r) { ocM[r] = min(m0 + r, 52); accM[r] = pwm_b[ocM[r]]; }
        #pragma unroll 2
        for (int k = 0; k < 64; ++k) {
            float vF = __half2float(PH[TFH + k * 34 + pxl]);
            float vC = __half2float(PH[TCH + k * 34 + pxl]);
            float vM = __half2float(PH[TMH + k * 34 + pxl]);
            #pragma unroll
            for (int r = 0; r < 4; ++r) accF[r] = fmaf(pwf_w[(f0 + r) * 64 + k], vF, accF[r]);
            #pragma unroll
            for (int r = 0; r < 9; ++r) accC[r] = fmaf(pwc_w[(c0 + r) * 64 + k], vC, accC[r]);
            #pragma unroll
            for (int r = 0; r < 7; ++r) accM[r] = fmaf(pwm_w[ocM[r] * 64 + k], vM, accM[r]);
        }
        if (lane < 32) {
            #pragma unroll
            for (int r = 0; r < 4; ++r)               // f: ox of taps 0..31
                P[SLOT + (pxl * 53 + (f0 + r)) * 4 + 0] = accF[r];
            #pragma unroll
            for (int r = 0; r < 9; ++r) {             // c: ox taps 32..51, oy taps 0..51
                int og = 32 + c0 + r;
                int e = (og < 52) ? (pxl * 53 + og) * 4
                                  : (pxl * 53 + (og - 52)) * 4 + 1;
                P[SLOT + e] = accC[r];
            }
            #pragma unroll
            for (int r = 0; r < 7; ++r) {             // m: scores + sparsity
                int o = m0 + r;
                if (o < 53) P[SBW + o * 33 + pxl] = accM[r];
            }
        }
    }
    __syncthreads();   // B2

    // ---- fused gated-softmax + coordpack: wave owns 4 px, lane = n ----
    #pragma unroll 1
    for (int i = 0; i < 4; ++i) {
        const int pl = wv * 4 + i;
        const float sp = P[SBW + 52 * 33 + pl];
        float z = -1e30f;
        if (lane < 52) {
            float s  = P[SBW + lane * 33 + pl];
            float sg = 1.0f / (1.0f + __expf(-(s - sp) * 10.0f));
            z = s + __logf(sg + 1e-10f);
        }
        float mx = z;
        #pragma unroll
        for (int d = 32; d >= 1; d >>= 1) mx = fmaxf(mx, __shfl_xor(mx, d));
        float e = (lane < 52) ? __expf(z - mx) : 0.0f;
        float sm = e;
        #pragma unroll
        for (int d = 32; d >= 1; d >>= 1) sm += __shfl_xor(sm, d);
        if (lane < 52) {
            const float mo = e / sm;
            const int e4 = SLOT + (pl * 53 + lane) * 4;
            float sx = (float)(x0 + pl) + p_n[lane]      + P[e4 + 0];
            float sy = (float)y         + p_n[52 + lane] + P[e4 + 1];
            float x0f = floorf(sx), y0f = floorf(sy);
            float wx1 = sx - x0f, wy1 = sy - y0f;
            float wx0 = 1.0f - wx1, wy0 = 1.0f - wy1;
            int xi = (int)x0f, yi = (int)y0f;
            int xi0 = min(max(xi, 0), 63), xi1 = min(max(xi + 1, 0), 63);
            int yi0 = min(max(yi, 0), 63), yi1 = min(max(yi + 1, 0), 63);
            bool vx0 = (xi >= 0)  & (xi <= 63);
            bool vx1 = (xi >= -1) & (xi <= 62);
            bool vy0 = (yi >= 0)  & (yi <= 63);
            bool vy1 = (yi >= -1) & (yi <= 62);
            float m00 = (vy0 & vx0) ? mo * wy0 * wx0 : 0.0f;
            float m01 = (vy0 & vx1) ? mo * wy0 * wx1 : 0.0f;
            float m10 = (vy1 & vx0) ? mo * wy1 * wx0 : 0.0f;
            float m11 = (vy1 & vx1) ? mo * wy1 * wx1 : 0.0f;
            int j0 = yi0 - ry0, j1 = yi1 - ry0;
            int c0_ = xi0 - x0 + 1, c1_ = xi1 - x0 + 1;
            uint32_t w0, w1;
            if ((j0 >= 0) & (j1 <= 4) & (c0_ >= 0) & (c1_ <= 35)) {
                w0 = (uint32_t)((j0 * 36 + c0_) * 128) | ((uint32_t)((j0 * 36 + c1_) * 128) << 16);
                w1 = (uint32_t)((j1 * 36 + c0_) * 128) | ((uint32_t)((j1 * 36 + c1_) * 128) << 16);
            } else {
                w0 = 0xFFFFFFFFu;
                w1 = (uint32_t)((yi0 << 6) | xi0) | ((uint32_t)((yi1 << 6) | xi1) << 16);
            }
            __half2 hA = __floats2half2_rn(m00, m01);
            __half2 hB = __floats2half2_rn(m10, m11);
            uint4 pkw;
            pkw.x = w0; pkw.y = w1;
            pkw.z = *reinterpret_cast<uint32_t*>(&hA);
            pkw.w = *reinterpret_cast<uint32_t*>(&hB);
            *reinterpret_cast<uint4*>(&PU[e4]) = pkw;
        }
    }
    __syncthreads();   // B3

    // ---- 52-tap gather from LDS window: perm + fdot2; lane = (px_sub, ch_quad) ----
    {
        const int sub = lane >> 4;      // 0..3
        const int c4  = lane & 15;      // channel quad
        const int spx = wv * 4 + sub;   // local px
        const int c4b = c4 * 8;
        const char* Pb = reinterpret_cast<const char*>(P);
        float4 agg = make_float4(0.f, 0.f, 0.f, 0.f);
        #pragma unroll 4
        for (int n = 0; n < 52; ++n) {
            const int e4 = SLOT + (spx * 53 + n) * 4;
            uint4 pk = *reinterpret_cast<const uint4*>(&PU[e4]);
            uint2 v00, v01, v10, v11;
            if (pk.x != 0xFFFFFFFFu) {
                v00 = *reinterpret_cast<const uint2*>(Pb + (pk.x & 0xFFFFu) + c4b);
                v01 = *reinterpret_cast<const uint2*>(Pb + (pk.x >> 16)     + c4b);
                v10 = *reinterpret_cast<const uint2*>(Pb + (pk.y & 0xFFFFu) + c4b);
                v11 = *reinterpret_cast<const uint2*>(Pb + (pk.y >> 16)     + c4b);
            } else {
                uint32_t a00 = pk.y & 0xFFFFu, a11 = pk.y >> 16;
                uint32_t a01 = (a00 & ~63u) | (a11 & 63u);
                uint32_t a10 = (a11 & ~63u) | (a00 & 63u);
                v00 = xb2[(a00 << 4) + c4];
                v01 = xb2[(a01 << 4) + c4];
                v10 = xb2[(a10 << 4) + c4];
                v11 = xb2[(a11 << 4) + c4];
            }
            agg.x = fdot2u(pk.z, __builtin_amdgcn_perm(v01.x, v00.x, 0x05040100u), agg.x);
            agg.y = fdot2u(pk.z, __builtin_amdgcn_perm(v01.x, v00.x, 0x07060302u), agg.y);
            agg.z = fdot2u(pk.z, __builtin_amdgcn_perm(v01.y, v00.y, 0x05040100u), agg.z);
            agg.w = fdot2u(pk.z, __builtin_amdgcn_perm(v01.y, v00.y, 0x07060302u), agg.w);
            agg.x = fdot2u(pk.w, __builtin_amdgcn_perm(v11.x, v10.x, 0x05040100u), agg.x);
            agg.y = fdot2u(pk.w, __builtin_amdgcn_perm(v11.x, v10.x, 0x07060302u), agg.y);
            agg.z = fdot2u(pk.w, __builtin_amdgcn_perm(v11.y, v10.y, 0x05040100u), agg.z);
            agg.w = fdot2u(pk.w, __builtin_amdgcn_perm(v11.y, v10.y, 0x07060302u), agg.w);
        }
        P[AGG + (c4 * 4 + 0) * 33 + spx] = agg.x;
        P[AGG + (c4 * 4 + 1) * 33 + spx] = agg.y;
        P[AGG + (c4 * 4 + 2) * 33 + spx] = agg.z;
        P[AGG + (c4 * 4 + 3) * 33 + spx] = agg.w;
    }
    __syncthreads();   // B4 (window + SLOT dead; AGG complete)

    // ---- pc 1x1: AGG -> PCB (window region); 8 rows/wave, lane = px ----
    {
        const int o0 = wv * 8;
        float acc[8];
        #pragma unroll
        for (int r = 0; r < 8; ++r) acc[r] = pc_b[o0 + r];
        #pragma unroll 4
        for (int k = 0; k < 64; ++k) {
            float v = P[AGG + k * 33 + pxl];
            #pragma unroll
            for (int r = 0; r < 8; ++r) acc[r] = fmaf(pc_w[(o0 + r) * 64 + k], v, acc[r]);
        }
        if (lane < 32) {
            #pragma unroll
            for (int r = 0; r < 8; ++r) P[PCB + (o0 + r) * 33 + pxl] = acc[r];
        }
    }
    __syncthreads();   // B5

    // ---- mlp1 (relu): PCB -> HB ----
    {
        const int o0 = wv * 8;
        float acc[8];
        #pragma unroll
        for (int r = 0; r < 8; ++r) acc[r] = b1[o0 + r];
        #pragma unroll 4
        for (int k = 0; k < 64; ++k) {
            float v = P[PCB + k * 33 + pxl];
            #pragma unroll
            for (int r = 0; r < 8; ++r) acc[r] = fmaf(w1[(o0 + r) * 64 + k], v, acc[r]);
        }
        if (lane < 32) {
            #pragma unroll
            for (int r = 0; r < 8; ++r) P[HB + (o0 + r) * 33 + pxl] = fmaxf(acc[r], 0.0f);
        }
    }
    __syncthreads();   // B6

    // ---- mlp2 + residual + coalesced NCHW store ----
    {
        const int o0 = wv * 8;
        float acc[8];
        #pragma unroll
        for (int r = 0; r < 8; ++r) acc[r] = b2[o0 + r];
        #pragma unroll 4
        for (int k = 0; k < 64; ++k) {
            float v = P[HB + k * 33 + pxl];
            #pragma unroll
            for (int r = 0; r < 8; ++r) acc[r] = fmaf(w2[(o0 + r) * 64 + k], v, acc[r]);
        }
        if (lane < 32) {
            #pragma unroll
            for (int r = 0; r < 8; ++r) {
                int o = o0 + r;
                size_t idx = (((size_t)b * 64 + o) * 64 + y) * 64 + x0 + pxl;
                out[idx] = acc[r] + x[idx];
            }
        }
    }
}

extern "C" void kernel_launch(void* const* d_in, const int* in_sizes, int n_in,
                              void* d_out, int out_size, void* d_ws, size_t ws_size,
                              hipStream_t stream) {
    const float* x     = (const float*)d_in[0];
    const float* p_n   = (const float*)d_in[1];
    const float* dwf_w = (const float*)d_in[2];
    const float* dwf_b = (const float*)d_in[3];
    const float* pwf_w = (const float*)d_in[4];
    const float* pwf_b = (const float*)d_in[5];
    const float* dwc_w = (const float*)d_in[6];
    const float* dwc_b = (const float*)d_in[7];
    const float* pwc_w = (const float*)d_in[8];
    const float* pwc_b = (const float*)d_in[9];
    const float* dwm_w = (const float*)d_in[10];
    const float* dwm_b = (const float*)d_in[11];
    const float* pwm_w = (const float*)d_in[12];
    const float* pwm_b = (const float*)d_in[13];
    const float* pc_w  = (const float*)d_in[14];
    const float* pc_b  = (const float*)d_in[15];
    const float* w1    = (const float*)d_in[16];
    const float* b1    = (const float*)d_in[17];
    const float* w2    = (const float*)d_in[18];
    const float* b2    = (const float*)d_in[19];

    __half* xth = (__half*)d_ws;      // 2 MB NHWC fp16 copy of x
    float* outp = (float*)d_out;

    hipLaunchKernelGGL(transpose_half, dim3(BB * HH), dim3(256), 0, stream, x, xth);
    hipLaunchKernelGGL(crossd_main, dim3(BB * HH * 2), dim3(512), 0, stream,
                       xth, x, p_n,
                       dwf_w, dwf_b, pwf_w, pwf_b,
                       dwc_w, dwc_b, pwc_w, pwc_b,
                       dwm_w, dwm_b, pwm_w, pwm_b,
                       pc_w, pc_b, w1, b1, w2, b2, outp);
}

// Round 10
// 57.682 us; speedup vs baseline: 1.4574x; 1.4574x over previous
//
#include <hip/hip_runtime.h>
#include <hip/hip_fp16.h>
#include <cmath>

#define BB 4
#define HH 64
#define WW 64

// ---- LDS pool: words total 37344 = 149376 B ----
#define SLOT  17920     // words: [52 n][64 px] x4 w {ox,oy,-,-} -> packed taps; later pcb/h1b
#define SBW   31232     // words: [53][67] scores -> mod
#define POOLW 37344
// half-indexed bases (PH)
#define WIN_H 0         // [5][64][64] fp16 window (20480 halves)
#define TF_H  20480     // t_f [64 px][80] fp16
#define TC_H  25600
#define TM_H  30720
#define AGG_H 69568     // agg [64 px][80] fp16 (words 34784..37344)
#define PCB_H 35840     // pc out [64 px][80] fp16 (overlays SLOT, dead after gather)
#define H1_H  40960     // h1     [64 px][80] fp16 (overlays SLOT)

typedef _Float16 f16x8 __attribute__((ext_vector_type(8)));
typedef float    f32x4 __attribute__((ext_vector_type(4)));

// ---------------- NCHW -> NHWC fp16 transpose (LDS tiled) ----------------
__global__ __launch_bounds__(256) void transpose_half(const float* __restrict__ x,
                                                      __half* __restrict__ xth) {
    int bid = blockIdx.x;
    int b = bid >> 6, y = bid & 63;
    __shared__ float tile[64][65];
    const float* xp = x + ((size_t)b * 64 * HH + y) * WW;
    #pragma unroll
    for (int k = 0; k < 16; ++k) {
        int idx = threadIdx.x + (k << 8);
        int c = idx >> 6, w = idx & 63;
        tile[c][w] = xp[(size_t)c * HH * WW + w];
    }
    __syncthreads();
    __half* op = xth + ((size_t)(b * HH + y) * WW) * 64;
    #pragma unroll
    for (int k = 0; k < 16; ++k) {
        int idx = threadIdx.x + (k << 8);
        int w = idx >> 6, c = idx & 63;
        op[(size_t)w * 64 + c] = __float2half(tile[c][w]);
    }
}

// one 16x16 output tile per wave: D = W(64x64 f32 global) x act(PH [px][80] f16) + bias
__device__ inline f32x4 tile_gemm64(const __half* PH, int actH,
                                    const float* __restrict__ W,
                                    const float* __restrict__ Bv,
                                    int m_t, int n_t, int lane) {
    const int row = m_t * 16 + (lane & 15);
    const int kg  = (lane >> 4) * 8;
    const float* wr = W + row * 64 + kg;
    float4 wa0 = *reinterpret_cast<const float4*>(wr);
    float4 wa1 = *reinterpret_cast<const float4*>(wr + 4);
    float4 wb0 = *reinterpret_cast<const float4*>(wr + 32);
    float4 wb1 = *reinterpret_cast<const float4*>(wr + 36);
    f16x8 a0, a1;
    a0[0]=(_Float16)wa0.x; a0[1]=(_Float16)wa0.y; a0[2]=(_Float16)wa0.z; a0[3]=(_Float16)wa0.w;
    a0[4]=(_Float16)wa1.x; a0[5]=(_Float16)wa1.y; a0[6]=(_Float16)wa1.z; a0[7]=(_Float16)wa1.w;
    a1[0]=(_Float16)wb0.x; a1[1]=(_Float16)wb0.y; a1[2]=(_Float16)wb0.z; a1[3]=(_Float16)wb0.w;
    a1[4]=(_Float16)wb1.x; a1[5]=(_Float16)wb1.y; a1[6]=(_Float16)wb1.z; a1[7]=(_Float16)wb1.w;
    const int px = n_t * 16 + (lane & 15);
    f16x8 b0 = *reinterpret_cast<const f16x8*>(&PH[actH + px * 80 + kg]);
    f16x8 b1 = *reinterpret_cast<const f16x8*>(&PH[actH + px * 80 + 32 + kg]);
    f32x4 d;
    const int r0 = m_t * 16 + ((lane >> 4) << 2);
    #pragma unroll
    for (int r = 0; r < 4; ++r) d[r] = Bv[r0 + r];
    d = __builtin_amdgcn_mfma_f32_16x16x32_f16(a0, b0, d, 0, 0, 0);
    d = __builtin_amdgcn_mfma_f32_16x16x32_f16(a1, b1, d, 0, 0, 0);
    return d;
}

// ---------------- fused main: 1 block (16 waves, 1024 thr) per image row ----------------
__global__ __launch_bounds__(1024, 4) void crossd_main(
    const __half* __restrict__ xth, const float* __restrict__ x,
    const float* __restrict__ p_n,
    const float* __restrict__ dwf_w, const float* __restrict__ dwf_b,
    const float* __restrict__ pwf_w, const float* __restrict__ pwf_b,
    const float* __restrict__ dwc_w, const float* __restrict__ dwc_b,
    const float* __restrict__ pwc_w, const float* __restrict__ pwc_b,
    const float* __restrict__ dwm_w, const float* __restrict__ dwm_b,
    const float* __restrict__ pwm_w, const float* __restrict__ pwm_b,
    const float* __restrict__ pc_w, const float* __restrict__ pc_b,
    const float* __restrict__ w1, const float* __restrict__ b1,
    const float* __restrict__ w2, const float* __restrict__ b2,
    float* __restrict__ out)
{
    __shared__ float P[POOLW];
    uint32_t* PU = reinterpret_cast<uint32_t*>(P);
    __half*   PH = reinterpret_cast<__half*>(P);
    const int tid  = threadIdx.x;
    const int lane = tid & 63;
    const int wv   = __builtin_amdgcn_readfirstlane(tid >> 6);   // 0..15
    const int b = blockIdx.x >> 6, y = blockIdx.x & 63;
    const int ry0 = min(max(y - 1, 0), 59);                      // window rows ry0..ry0+4
    const __half* xbh = xth + (size_t)b * (HH * WW * 64);
    const uint2* xb2 = reinterpret_cast<const uint2*>(xbh);

    // ---- phase 0: stage 5-row fp16 window into LDS ----
    {
        const int px = tid >> 4, c4v = tid & 15;
        uint2* WINu = reinterpret_cast<uint2*>(P);
        #pragma unroll
        for (int j = 0; j < 5; ++j) {
            int ry = ry0 + j;
            WINu[(j * 64 + px) * 16 + c4v] = xb2[((ry << 6) + px) * 16 + c4v];
        }
    }
    __syncthreads();   // B0

    // ---- depthwise 3x3 from window: wave = 4 px, lane = ch; fp16 t-buffers [px][80] ----
    {
        const int c = lane;
        float wf9[9], wc9[9], wm9[9];
        #pragma unroll
        for (int k9 = 0; k9 < 9; ++k9) {
            wf9[k9] = dwf_w[c * 9 + k9];
            wc9[k9] = dwc_w[c * 9 + k9];
            wm9[k9] = dwm_w[c * 9 + k9];
        }
        const float bf = dwf_b[c], bc = dwc_b[c], bm = dwm_b[c];
        #pragma unroll
        for (int i = 0; i < 4; ++i) {
            const int px = wv * 4 + i;
            float af = bf, ac = bc, am = bm;
            #pragma unroll
            for (int dy = 0; dy < 3; ++dy) {
                int yy = y + dy - 1;
                if (yy < 0 || yy >= HH) continue;
                int j = yy - ry0;
                #pragma unroll
                for (int dx = 0; dx < 3; ++dx) {
                    int xx = px + dx - 1;
                    if (xx < 0 || xx >= WW) continue;
                    float v = __half2float(PH[(j * 64 + xx) * 64 + c]);
                    int k = dy * 3 + dx;
                    af = fmaf(v, wf9[k], af);
                    ac = fmaf(v, wc9[k], ac);
                    am = fmaf(v, wm9[k], am);
                }
            }
            PH[TF_H + px * 80 + c] = __float2half(af);
            PH[TC_H + px * 80 + c] = __float2half(ac);
            PH[TM_H + px * 80 + c] = __float2half(am);
        }
    }
    __syncthreads();   // B1

    // ---- fused f+c+m pointwise via MFMA: 11 m-tiles (2 f, 5 c, 4 m) x 4 n-tiles ----
    {
        const int n_t = wv & 3;
        const int g   = wv >> 2;
        #pragma unroll
        for (int t = 0; t < 3; ++t) {
            const int m_t = g + t * 4;
            if (m_t < 11) {
                const float *Wb, *Bvb; int rows, actH, r0b, br;
                if (m_t < 2)      { Wb=pwf_w; Bvb=pwf_b; rows=32; actH=TF_H; r0b=m_t*16;       br=0; }
                else if (m_t < 7) { Wb=pwc_w; Bvb=pwc_b; rows=72; actH=TC_H; r0b=(m_t-2)*16;   br=1; }
                else              { Wb=pwm_w; Bvb=pwm_b; rows=53; actH=TM_H; r0b=(m_t-7)*16;   br=2; }
                const int rl  = min(r0b + (lane & 15), rows - 1);
                const int kg  = (lane >> 4) * 8;
                const float* wr = Wb + rl * 64 + kg;
                float4 wa0 = *reinterpret_cast<const float4*>(wr);
                float4 wa1 = *reinterpret_cast<const float4*>(wr + 4);
                float4 wb0 = *reinterpret_cast<const float4*>(wr + 32);
                float4 wb1 = *reinterpret_cast<const float4*>(wr + 36);
                f16x8 a0, a1;
                a0[0]=(_Float16)wa0.x; a0[1]=(_Float16)wa0.y; a0[2]=(_Float16)wa0.z; a0[3]=(_Float16)wa0.w;
                a0[4]=(_Float16)wa1.x; a0[5]=(_Float16)wa1.y; a0[6]=(_Float16)wa1.z; a0[7]=(_Float16)wa1.w;
                a1[0]=(_Float16)wb0.x; a1[1]=(_Float16)wb0.y; a1[2]=(_Float16)wb0.z; a1[3]=(_Float16)wb0.w;
                a1[4]=(_Float16)wb1.x; a1[5]=(_Float16)wb1.y; a1[6]=(_Float16)wb1.z; a1[7]=(_Float16)wb1.w;
                const int px = n_t * 16 + (lane & 15);
                f16x8 b0 = *reinterpret_cast<const f16x8*>(&PH[actH + px * 80 + kg]);
                f16x8 b1 = *reinterpret_cast<const f16x8*>(&PH[actH + px * 80 + 32 + kg]);
                f32x4 d;
                const int rr0 = r0b + ((lane >> 4) << 2);
                #pragma unroll
                for (int r = 0; r < 4; ++r) d[r] = Bvb[min(rr0 + r, rows - 1)];
                d = __builtin_amdgcn_mfma_f32_16x16x32_f16(a0, b0, d, 0, 0, 0);
                d = __builtin_amdgcn_mfma_f32_16x16x32_f16(a1, b1, d, 0, 0, 0);
                #pragma unroll
                for (int r = 0; r < 4; ++r) {
                    const int rb = rr0 + r;
                    if (rb < rows) {
                        const float v = d[r];
                        if (br == 0) {
                            P[SLOT + (rb * 64 + px) * 4 + 0] = v;
                        } else if (br == 1) {
                            int og = 32 + rb;
                            if (og < 52) P[SLOT + (og * 64 + px) * 4 + 0] = v;
                            else         P[SLOT + ((og - 52) * 64 + px) * 4 + 1] = v;
                        } else {
                            P[SBW + rb * 67 + px] = v;
                        }
                    }
                }
            }
        }
    }
    __syncthreads();   // B2

    // ---- gated softmax over 52 scores (in SB): lane = n, wave owns 4 px ----
    #pragma unroll
    for (int i = 0; i < 4; ++i) {
        const int px = wv * 4 + i;
        const float sp = P[SBW + 52 * 67 + px];
        float z = -1e30f;
        if (lane < 52) {
            float s  = P[SBW + lane * 67 + px];
            float sg = 1.0f / (1.0f + __expf(-(s - sp) * 10.0f));
            z = s + __logf(sg + 1e-10f);
        }
        float mx = z;
        #pragma unroll
        for (int d = 32; d >= 1; d >>= 1) mx = fmaxf(mx, __shfl_xor(mx, d));
        float e = (lane < 52) ? __expf(z - mx) : 0.0f;
        float sm = e;
        #pragma unroll
        for (int d = 32; d >= 1; d >>= 1) sm += __shfl_xor(sm, d);
        if (lane < 52) P[SBW + lane * 67 + px] = e / sm;
    }
    __syncthreads();   // B3

    // ---- coordpack: rewrite each SLOT entry as {4 u16 LDS offsets, 4 half weights} ----
    {
        const int ppx = tid & 63;
        const int g   = tid >> 6;
        for (int n = g; n < 52; n += 16) {
            const int e4 = SLOT + (n * 64 + ppx) * 4;
            float sx = (float)ppx + p_n[n]      + P[e4 + 0];
            float sy = (float)y   + p_n[52 + n] + P[e4 + 1];
            float mo = P[SBW + n * 67 + ppx];
            float x0f = floorf(sx), y0f = floorf(sy);
            float wx1 = sx - x0f, wy1 = sy - y0f;
            float wx0 = 1.0f - wx1, wy0 = 1.0f - wy1;
            int x0 = (int)x0f, y0 = (int)y0f;
            int xi0 = min(max(x0, 0), 63), xi1 = min(max(x0 + 1, 0), 63);
            int yi0 = min(max(y0, 0), 63), yi1 = min(max(y0 + 1, 0), 63);
            bool vx0 = (x0 >= 0)  & (x0 <= 63);
            bool vx1 = (x0 >= -1) & (x0 <= 62);
            bool vy0 = (y0 >= 0)  & (y0 <= 63);
            bool vy1 = (y0 >= -1) & (y0 <= 62);
            float m00 = (vy0 & vx0) ? mo * wy0 * wx0 : 0.0f;
            float m01 = (vy0 & vx1) ? mo * wy0 * wx1 : 0.0f;
            float m10 = (vy1 & vx0) ? mo * wy1 * wx0 : 0.0f;
            float m11 = (vy1 & vx1) ? mo * wy1 * wx1 : 0.0f;
            int j0 = yi0 - ry0, j1 = yi1 - ry0;
            uint32_t w0, w1;
            if ((j0 >= 0) & (j1 <= 4)) {
                w0 = (uint32_t)((j0 * 64 + xi0) * 128) | ((uint32_t)((j0 * 64 + xi1) * 128) << 16);
                w1 = (uint32_t)((j1 * 64 + xi0) * 128) | ((uint32_t)((j1 * 64 + xi1) * 128) << 16);
            } else {
                w0 = 0xFFFFFFFFu;
                w1 = (uint32_t)((yi0 << 6) | xi0) | ((uint32_t)((yi1 << 6) | xi1) << 16);
            }
            __half2 hA = __floats2half2_rn(m00, m01);
            __half2 hB = __floats2half2_rn(m10, m11);
            uint4 pkw;
            pkw.x = w0; pkw.y = w1;
            pkw.z = *reinterpret_cast<uint32_t*>(&hA);
            pkw.w = *reinterpret_cast<uint32_t*>(&hB);
            *reinterpret_cast<uint4*>(&PU[e4]) = pkw;
        }
    }
    __syncthreads();   // B4

    // ---- 52-tap gather from LDS window; agg -> fp16 [px][80] ----
    typedef _Float16 half2v __attribute__((ext_vector_type(2)));
    {
        const int sub = lane >> 4;
        const int c4  = lane & 15;
        const int spx = wv * 4 + sub;
        const int c4b = c4 * 8;
        const char* Pb = reinterpret_cast<const char*>(P);
        float4 agg = make_float4(0.f, 0.f, 0.f, 0.f);
        #pragma unroll 4
        for (int n = 0; n < 52; ++n) {
            const int e4 = SLOT + (n * 64 + spx) * 4;
            uint4 pk = *reinterpret_cast<const uint4*>(&PU[e4]);
            uint2 v00, v01, v10, v11;
            if (pk.x != 0xFFFFFFFFu) {
                v00 = *reinterpret_cast<const uint2*>(Pb + (pk.x & 0xFFFFu) + c4b);
                v01 = *reinterpret_cast<const uint2*>(Pb + (pk.x >> 16)     + c4b);
                v10 = *reinterpret_cast<const uint2*>(Pb + (pk.y & 0xFFFFu) + c4b);
                v11 = *reinterpret_cast<const uint2*>(Pb + (pk.y >> 16)     + c4b);
            } else {
                uint32_t a00 = pk.y & 0xFFFFu, a11 = pk.y >> 16;
                uint32_t a01 = (a00 & ~63u) | (a11 & 63u);
                uint32_t a10 = (a11 & ~63u) | (a00 & 63u);
                v00 = xb2[(a00 << 4) + c4];
                v01 = xb2[(a01 << 4) + c4];
                v10 = xb2[(a10 << 4) + c4];
                v11 = xb2[(a11 << 4) + c4];
            }
            __half2 hA = *reinterpret_cast<const __half2*>(&pk.z);
            __half2 hB = *reinterpret_cast<const __half2*>(&pk.w);
            float m00 = __low2float(hA), m01 = __high2float(hA);
            float m10 = __low2float(hB), m11 = __high2float(hB);
            #define ACC4(u, m) { \
                __half2 hlo = *reinterpret_cast<const __half2*>(&u.x); \
                __half2 hhi = *reinterpret_cast<const __half2*>(&u.y); \
                float2 flo = __half22float2(hlo), fhi = __half22float2(hhi); \
                agg.x = fmaf(m, flo.x, agg.x); agg.y = fmaf(m, flo.y, agg.y); \
                agg.z = fmaf(m, fhi.x, agg.z); agg.w = fmaf(m, fhi.y, agg.w); }
            ACC4(v00, m00); ACC4(v01, m01); ACC4(v10, m10); ACC4(v11, m11);
            #undef ACC4
        }
        __half2 p0 = __floats2half2_rn(agg.x, agg.y);
        __half2 p1 = __floats2half2_rn(agg.z, agg.w);
        uint2 pk2;
        pk2.x = *reinterpret_cast<uint32_t*>(&p0);
        pk2.y = *reinterpret_cast<uint32_t*>(&p1);
        *reinterpret_cast<uint2*>(&PH[AGG_H + spx * 80 + c4 * 4]) = pk2;
    }
    __syncthreads();   // B5

    // ---- pc 1x1 via MFMA: AGG -> PCB ----
    {
        f32x4 d = tile_gemm64(PH, AGG_H, pc_w, pc_b, wv >> 2, wv & 3, lane);
        const int px = (wv & 3) * 16 + (lane & 15);
        const int o0 = (wv >> 2) * 16 + ((lane >> 4) << 2);
        __half2 p0 = __floats2half2_rn(d[0], d[1]);
        __half2 p1 = __floats2half2_rn(d[2], d[3]);
        uint2 pk2;
        pk2.x = *reinterpret_cast<uint32_t*>(&p0);
        pk2.y = *reinterpret_cast<uint32_t*>(&p1);
        *reinterpret_cast<uint2*>(&PH[PCB_H + px * 80 + o0]) = pk2;
    }
    __syncthreads();   // B6

    // ---- mlp1 (relu) via MFMA: PCB -> H1 ----
    {
        f32x4 d = tile_gemm64(PH, PCB_H, w1, b1, wv >> 2, wv & 3, lane);
        #pragma unroll
        for (int r = 0; r < 4; ++r) d[r] = fmaxf(d[r], 0.0f);
        const int px = (wv & 3) * 16 + (lane & 15);
        const int o0 = (wv >> 2) * 16 + ((lane >> 4) << 2);
        __half2 p0 = __floats2half2_rn(d[0], d[1]);
        __half2 p1 = __floats2half2_rn(d[2], d[3]);
        uint2 pk2;
        pk2.x = *reinterpret_cast<uint32_t*>(&p0);
        pk2.y = *reinterpret_cast<uint32_t*>(&p1);
        *reinterpret_cast<uint2*>(&PH[H1_H + px * 80 + o0]) = pk2;
    }
    __syncthreads();   // B7

    // ---- mlp2 via MFMA + residual + NCHW store ----
    {
        f32x4 d = tile_gemm64(PH, H1_H, w2, b2, wv >> 2, wv & 3, lane);
        const int px = (wv & 3) * 16 + (lane & 15);
        const int o0 = (wv >> 2) * 16 + ((lane >> 4) << 2);
        #pragma unroll
        for (int r = 0; r < 4; ++r) {
            const int o = o0 + r;
            size_t idx = (((size_t)b * 64 + o) * 64 + y) * 64 + px;
            out[idx] = d[r] + x[idx];
        }
    }
}

extern "C" void kernel_launch(void* const* d_in, const int* in_sizes, int n_in,
                              void* d_out, int out_size, void* d_ws, size_t ws_size,
                              hipStream_t stream) {
    const float* x     = (const float*)d_in[0];
    const float* p_n   = (const float*)d_in[1];
    const float* dwf_w = (const float*)d_in[2];
    const float* dwf_b = (const float*)d_in[3];
    const float* pwf_w = (const float*)d_in[4];
    const float* pwf_b = (const float*)d_in[5];
    const float* dwc_w = (const float*)d_in[6];
    const float* dwc_b = (const float*)d_in[7];
    const float* pwc_w = (const float*)d_in[8];
    const float* pwc_b = (const float*)d_in[9];
    const float* dwm_w = (const float*)d_in[10];
    const float* dwm_b = (const float*)d_in[11];
    const float* pwm_w = (const float*)d_in[12];
    const float* pwm_b = (const float*)d_in[13];
    const float* pc_w  = (const float*)d_in[14];
    const float* pc_b  = (const float*)d_in[15];
    const float* w1    = (const float*)d_in[16];
    const float* b1    = (const float*)d_in[17];
    const float* w2    = (const float*)d_in[18];
    const float* b2    = (const float*)d_in[19];

    __half* xth = (__half*)d_ws;      // 2 MB NHWC fp16 copy of x
    float* outp = (float*)d_out;

    hipLaunchKernelGGL(transpose_half, dim3(BB * HH), dim3(256), 0, stream, x, xth);
    hipLaunchKernelGGL(crossd_main, dim3(BB * HH), dim3(1024), 0, stream,
                       xth, x, p_n,
                       dwf_w, dwf_b, pwf_w, pwf_b,
                       dwc_w, dwc_b, pwc_w, pwc_b,
                       dwm_w, dwm_b, pwm_w, pwm_b,
                       pc_w, pc_b, w1, b1, w2, b2, outp);
}

// Round 11
// 50.406 us; speedup vs baseline: 1.6678x; 1.1443x over previous
//
#include <hip/hip_runtime.h>
#include <hip/hip_fp16.h>
#include <cmath>

#define BB 4
#define HH 64
#define WW 64

// ---- LDS pool: words, total 37154 = 148.6 KB ----
// window: [5][64][68] fp16 (col stride 68 halves = 136 B: 8B-aligned b64, bank-shift 2/col)
#define OFFW  18560     // [104][65] f32: ox rows 0..51, oy rows 52..103
#define SBW   25320     // [53][67] f32: scores -> mod
#define CMAP  28871     // [25][65] f32: per-pixel 5x5 cell weight map
#define FLBC  30496     // fallback counter (1 w)
#define FLB   30497     // fallback list, 2048 x uint2
#define POOLW 37154
// half-indexed bases
#define TF_H  21760     // t_f [64 px][80] fp16
#define TC_H  26880
#define TM_H  32000
#define AGG_H 69188     // agg [64 px][80] fp16 (words 34594..37154)
#define PCB_H 37120     // pc out, overlays OFFW (dead after coordpack)
#define H1_H  42240     // h1, overlays OFFW+SBW

typedef _Float16 f16x8 __attribute__((ext_vector_type(8)));
typedef float    f32x4 __attribute__((ext_vector_type(4)));

// ---------------- NCHW -> NHWC fp16 transpose (LDS tiled) ----------------
__global__ __launch_bounds__(256) void transpose_half(const float* __restrict__ x,
                                                      __half* __restrict__ xth) {
    int bid = blockIdx.x;
    int b = bid >> 6, y = bid & 63;
    __shared__ float tile[64][65];
    const float* xp = x + ((size_t)b * 64 * HH + y) * WW;
    #pragma unroll
    for (int k = 0; k < 16; ++k) {
        int idx = threadIdx.x + (k << 8);
        int c = idx >> 6, w = idx & 63;
        tile[c][w] = xp[(size_t)c * HH * WW + w];
    }
    __syncthreads();
    __half* op = xth + ((size_t)(b * HH + y) * WW) * 64;
    #pragma unroll
    for (int k = 0; k < 16; ++k) {
        int idx = threadIdx.x + (k << 8);
        int w = idx >> 6, c = idx & 63;
        op[(size_t)w * 64 + c] = __float2half(tile[c][w]);
    }
}

// one 16x16 output tile per wave: D = W(64x64 f32 global) x act(PH [px][80] f16) + bias
__device__ inline f32x4 tile_gemm64(const __half* PH, int actH,
                                    const float* __restrict__ W,
                                    const float* __restrict__ Bv,
                                    int m_t, int n_t, int lane) {
    const int row = m_t * 16 + (lane & 15);
    const int kg  = (lane >> 4) * 8;
    const float* wr = W + row * 64 + kg;
    float4 wa0 = *reinterpret_cast<const float4*>(wr);
    float4 wa1 = *reinterpret_cast<const float4*>(wr + 4);
    float4 wb0 = *reinterpret_cast<const float4*>(wr + 32);
    float4 wb1 = *reinterpret_cast<const float4*>(wr + 36);
    f16x8 a0, a1;
    a0[0]=(_Float16)wa0.x; a0[1]=(_Float16)wa0.y; a0[2]=(_Float16)wa0.z; a0[3]=(_Float16)wa0.w;
    a0[4]=(_Float16)wa1.x; a0[5]=(_Float16)wa1.y; a0[6]=(_Float16)wa1.z; a0[7]=(_Float16)wa1.w;
    a1[0]=(_Float16)wb0.x; a1[1]=(_Float16)wb0.y; a1[2]=(_Float16)wb0.z; a1[3]=(_Float16)wb0.w;
    a1[4]=(_Float16)wb1.x; a1[5]=(_Float16)wb1.y; a1[6]=(_Float16)wb1.z; a1[7]=(_Float16)wb1.w;
    const int px = n_t * 16 + (lane & 15);
    f16x8 b0 = *reinterpret_cast<const f16x8*>(&PH[actH + px * 80 + kg]);
    f16x8 b1 = *reinterpret_cast<const f16x8*>(&PH[actH + px * 80 + 32 + kg]);
    f32x4 d;
    const int r0 = m_t * 16 + ((lane >> 4) << 2);
    #pragma unroll
    for (int r = 0; r < 4; ++r) d[r] = Bv[r0 + r];
    d = __builtin_amdgcn_mfma_f32_16x16x32_f16(a0, b0, d, 0, 0, 0);
    d = __builtin_amdgcn_mfma_f32_16x16x32_f16(a1, b1, d, 0, 0, 0);
    return d;
}

// ---------------- fused main: 1 block (16 waves, 1024 thr) per image row ----------------
__global__ __launch_bounds__(1024, 4) void crossd_main(
    const __half* __restrict__ xth, const float* __restrict__ x,
    const float* __restrict__ p_n,
    const float* __restrict__ dwf_w, const float* __restrict__ dwf_b,
    const float* __restrict__ pwf_w, const float* __restrict__ pwf_b,
    const float* __restrict__ dwc_w, const float* __restrict__ dwc_b,
    const float* __restrict__ pwc_w, const float* __restrict__ pwc_b,
    const float* __restrict__ dwm_w, const float* __restrict__ dwm_b,
    const float* __restrict__ pwm_w, const float* __restrict__ pwm_b,
    const float* __restrict__ pc_w, const float* __restrict__ pc_b,
    const float* __restrict__ w1, const float* __restrict__ b1,
    const float* __restrict__ w2, const float* __restrict__ b2,
    float* __restrict__ out)
{
    __shared__ float P[POOLW];
    uint32_t* PU = reinterpret_cast<uint32_t*>(P);
    __half*   PH = reinterpret_cast<__half*>(P);
    const int tid  = threadIdx.x;
    const int lane = tid & 63;
    const int wv   = __builtin_amdgcn_readfirstlane(tid >> 6);   // 0..15
    const int b = blockIdx.x >> 6, y = blockIdx.x & 63;
    const int ry0 = min(max(y - 1, 0), 59);                      // window rows ry0..ry0+4
    const __half* xbh = xth + (size_t)b * (HH * WW * 64);
    const uint2* xb2 = reinterpret_cast<const uint2*>(xbh);

    // ---- phase 0: stage 5-row fp16 window (stride-68 cols) + zero CMAP/counter ----
    {
        for (int idx = tid; idx < 5 * 64 * 16; idx += 1024) {
            int j = idx >> 10;
            int rem = idx & 1023;
            int px = rem >> 4, c4v = idx & 15;
            *reinterpret_cast<uint2*>(&PH[(j * 64 + px) * 68 + c4v * 4]) =
                xb2[(((ry0 + j) << 6) + px) * 16 + c4v];
        }
        for (int i = tid; i < 25 * 65 + 1; i += 1024) P[CMAP + i] = 0.0f;  // CMAP + FLBC
    }
    __syncthreads();   // B0

    // ---- depthwise 3x3 from window: wave = 4 px, lane = ch; fp16 t-buffers [px][80] ----
    {
        const int c = lane;
        float wf9[9], wc9[9], wm9[9];
        #pragma unroll
        for (int k9 = 0; k9 < 9; ++k9) {
            wf9[k9] = dwf_w[c * 9 + k9];
            wc9[k9] = dwc_w[c * 9 + k9];
            wm9[k9] = dwm_w[c * 9 + k9];
        }
        const float bf = dwf_b[c], bc = dwc_b[c], bm = dwm_b[c];
        #pragma unroll
        for (int i = 0; i < 4; ++i) {
            const int px = wv * 4 + i;
            float af = bf, ac = bc, am = bm;
            #pragma unroll
            for (int dy = 0; dy < 3; ++dy) {
                int yy = y + dy - 1;
                if (yy < 0 || yy >= HH) continue;
                int j = yy - ry0;
                #pragma unroll
                for (int dx = 0; dx < 3; ++dx) {
                    int xx = px + dx - 1;
                    if (xx < 0 || xx >= WW) continue;
                    float v = __half2float(PH[(j * 64 + xx) * 68 + c]);
                    int k = dy * 3 + dx;
                    af = fmaf(v, wf9[k], af);
                    ac = fmaf(v, wc9[k], ac);
                    am = fmaf(v, wm9[k], am);
                }
            }
            PH[TF_H + px * 80 + c] = __float2half(af);
            PH[TC_H + px * 80 + c] = __float2half(ac);
            PH[TM_H + px * 80 + c] = __float2half(am);
        }
    }
    __syncthreads();   // B1

    // ---- fused f+c+m pointwise via MFMA: 11 m-tiles (2 f, 5 c, 4 m) x 4 n-tiles ----
    {
        const int n_t = wv & 3;
        const int g   = wv >> 2;
        #pragma unroll
        for (int t = 0; t < 3; ++t) {
            const int m_t = g + t * 4;
            if (m_t < 11) {
                const float *Wb, *Bvb; int rows, actH, r0b, br;
                if (m_t < 2)      { Wb=pwf_w; Bvb=pwf_b; rows=32; actH=TF_H; r0b=m_t*16;     br=0; }
                else if (m_t < 7) { Wb=pwc_w; Bvb=pwc_b; rows=72; actH=TC_H; r0b=(m_t-2)*16; br=1; }
                else              { Wb=pwm_w; Bvb=pwm_b; rows=53; actH=TM_H; r0b=(m_t-7)*16; br=2; }
                const int rl  = min(r0b + (lane & 15), rows - 1);
                const int kg  = (lane >> 4) * 8;
                const float* wr = Wb + rl * 64 + kg;
                float4 wa0 = *reinterpret_cast<const float4*>(wr);
                float4 wa1 = *reinterpret_cast<const float4*>(wr + 4);
                float4 wb0 = *reinterpret_cast<const float4*>(wr + 32);
                float4 wb1 = *reinterpret_cast<const float4*>(wr + 36);
                f16x8 a0, a1;
                a0[0]=(_Float16)wa0.x; a0[1]=(_Float16)wa0.y; a0[2]=(_Float16)wa0.z; a0[3]=(_Float16)wa0.w;
                a0[4]=(_Float16)wa1.x; a0[5]=(_Float16)wa1.y; a0[6]=(_Float16)wa1.z; a0[7]=(_Float16)wa1.w;
                a1[0]=(_Float16)wb0.x; a1[1]=(_Float16)wb0.y; a1[2]=(_Float16)wb0.z; a1[3]=(_Float16)wb0.w;
                a1[4]=(_Float16)wb1.x; a1[5]=(_Float16)wb1.y; a1[6]=(_Float16)wb1.z; a1[7]=(_Float16)wb1.w;
                const int px = n_t * 16 + (lane & 15);
                f16x8 b0 = *reinterpret_cast<const f16x8*>(&PH[actH + px * 80 + kg]);
                f16x8 b1 = *reinterpret_cast<const f16x8*>(&PH[actH + px * 80 + 32 + kg]);
                f32x4 d;
                const int rr0 = r0b + ((lane >> 4) << 2);
                #pragma unroll
                for (int r = 0; r < 4; ++r) d[r] = Bvb[min(rr0 + r, rows - 1)];
                d = __builtin_amdgcn_mfma_f32_16x16x32_f16(a0, b0, d, 0, 0, 0);
                d = __builtin_amdgcn_mfma_f32_16x16x32_f16(a1, b1, d, 0, 0, 0);
                #pragma unroll
                for (int r = 0; r < 4; ++r) {
                    const int rb = rr0 + r;
                    if (rb < rows) {
                        const float v = d[r];
                        if (br == 2)      P[SBW + rb * 67 + px] = v;
                        else {
                            int og = (br == 0) ? rb : 32 + rb;    // 0..103 offset row
                            P[OFFW + og * 65 + px] = v;
                        }
                    }
                }
            }
        }
    }
    __syncthreads();   // B2

    // ---- gated softmax over 52 scores (in SB): lane = n, wave owns 4 px ----
    #pragma unroll
    for (int i = 0; i < 4; ++i) {
        const int px = wv * 4 + i;
        const float sp = P[SBW + 52 * 67 + px];
        float z = -1e30f;
        if (lane < 52) {
            float s  = P[SBW + lane * 67 + px];
            float sg = 1.0f / (1.0f + __expf(-(s - sp) * 10.0f));
            z = s + __logf(sg + 1e-10f);
        }
        float mx = z;
        #pragma unroll
        for (int d = 32; d >= 1; d >>= 1) mx = fmaxf(mx, __shfl_xor(mx, d));
        float e = (lane < 52) ? __expf(z - mx) : 0.0f;
        float sm = e;
        #pragma unroll
        for (int d = 32; d >= 1; d >>= 1) sm += __shfl_xor(sm, d);
        if (lane < 52) P[SBW + lane * 67 + px] = e / sm;
    }
    __syncthreads();   // B3

    // ---- coordpack: accumulate per-pixel 5x5 cell weight map via ds_add_f32 ----
    {
        const int ppx = tid & 63;
        const int g   = tid >> 6;
        for (int n = g; n < 52; n += 16) {
            float sx = (float)ppx + p_n[n]      + P[OFFW + n * 65 + ppx];
            float sy = (float)y   + p_n[52 + n] + P[OFFW + (52 + n) * 65 + ppx];
            float mo = P[SBW + n * 67 + ppx];
            float x0f = floorf(sx), y0f = floorf(sy);
            float wx1 = sx - x0f, wy1 = sy - y0f;
            float wx0 = 1.0f - wx1, wy0 = 1.0f - wy1;
            int xi = (int)x0f, yi = (int)y0f;      // true corner indices (may be -1..64)
            bool vx0 = (xi >= 0)  & (xi <= 63);
            bool vx1 = (xi >= -1) & (xi <= 62);
            bool vy0 = (yi >= 0)  & (yi <= 63);
            bool vy1 = (yi >= -1) & (yi <= 62);
            float m00 = (vy0 & vx0) ? mo * wy0 * wx0 : 0.0f;
            float m01 = (vy0 & vx1) ? mo * wy0 * wx1 : 0.0f;
            float m10 = (vy1 & vx0) ? mo * wy1 * wx0 : 0.0f;
            float m11 = (vy1 & vx1) ? mo * wy1 * wx1 : 0.0f;
            const int i0 = xi - ppx + 1, j0 = yi - ry0;
            #define PUSH(m, jj, ii, gx, gy) \
                if (m != 0.0f) { \
                    if ((jj) >= 0 && (jj) <= 4 && (ii) >= 0 && (ii) <= 4) { \
                        atomicAdd(&P[CMAP + ((jj) * 5 + (ii)) * 65 + ppx], m); \
                    } else { \
                        uint32_t a = (uint32_t)((gy) * 64 + (gx)); \
                        uint32_t sl = atomicAdd(&PU[FLBC], 1u); \
                        if (sl < 2048u) { \
                            PU[FLB + sl * 2]     = a | ((uint32_t)ppx << 16); \
                            PU[FLB + sl * 2 + 1] = __float_as_uint(m); \
                        } \
                    } \
                }
            PUSH(m00, j0,     i0,     xi,     yi);
            PUSH(m01, j0,     i0 + 1, xi + 1, yi);
            PUSH(m10, j0 + 1, i0,     xi,     yi + 1);
            PUSH(m11, j0 + 1, i0 + 1, xi + 1, yi + 1);
            #undef PUSH
        }
    }
    __syncthreads();   // B4

    // ---- 25-cell gather: W[cell][px] broadcast x window b64; agg -> fp16 [px][80] ----
    {
        const int sub = lane >> 4;
        const int c4  = lane & 15;
        const int spx = wv * 4 + sub;
        int co[5];
        #pragma unroll
        for (int i = 0; i < 5; ++i) co[i] = min(max(spx - 1 + i, 0), 63);
        float4 agg = make_float4(0.f, 0.f, 0.f, 0.f);
        #pragma unroll
        for (int j = 0; j < 5; ++j) {
            #pragma unroll
            for (int i = 0; i < 5; ++i) {
                float w = P[CMAP + (j * 5 + i) * 65 + spx];
                uint2 u = *reinterpret_cast<const uint2*>(&PH[(j * 64 + co[i]) * 68 + c4 * 4]);
                __half2 hlo = *reinterpret_cast<const __half2*>(&u.x);
                __half2 hhi = *reinterpret_cast<const __half2*>(&u.y);
                float2 flo = __half22float2(hlo), fhi = __half22float2(hhi);
                agg.x = fmaf(w, flo.x, agg.x); agg.y = fmaf(w, flo.y, agg.y);
                agg.z = fmaf(w, fhi.x, agg.z); agg.w = fmaf(w, fhi.y, agg.w);
            }
        }
        // rare out-of-neighborhood fallback (normally count == 0)
        const int cnt = min((int)PU[FLBC], 2048);
        for (int e = 0; e < cnt; ++e) {
            uint32_t ea = PU[FLB + e * 2];
            float m = __uint_as_float(PU[FLB + e * 2 + 1]);
            if ((int)(ea >> 16) == spx) {
                uint2 u = xb2[(ea & 0xFFFFu) * 16 + c4];
                __half2 hlo = *reinterpret_cast<const __half2*>(&u.x);
                __half2 hhi = *reinterpret_cast<const __half2*>(&u.y);
                float2 flo = __half22float2(hlo), fhi = __half22float2(hhi);
                agg.x = fmaf(m, flo.x, agg.x); agg.y = fmaf(m, flo.y, agg.y);
                agg.z = fmaf(m, fhi.x, agg.z); agg.w = fmaf(m, fhi.y, agg.w);
            }
        }
        __half2 p0 = __floats2half2_rn(agg.x, agg.y);
        __half2 p1 = __floats2half2_rn(agg.z, agg.w);
        uint2 pk2;
        pk2.x = *reinterpret_cast<uint32_t*>(&p0);
        pk2.y = *reinterpret_cast<uint32_t*>(&p1);
        *reinterpret_cast<uint2*>(&PH[AGG_H + spx * 80 + c4 * 4]) = pk2;
    }
    __syncthreads();   // B5

    // ---- pc 1x1 via MFMA: AGG -> PCB ----
    {
        f32x4 d = tile_gemm64(PH, AGG_H, pc_w, pc_b, wv >> 2, wv & 3, lane);
        const int px = (wv & 3) * 16 + (lane & 15);
        const int o0 = (wv >> 2) * 16 + ((lane >> 4) << 2);
        __half2 p0 = __floats2half2_rn(d[0], d[1]);
        __half2 p1 = __floats2half2_rn(d[2], d[3]);
        uint2 pk2;
        pk2.x = *reinterpret_cast<uint32_t*>(&p0);
        pk2.y = *reinterpret_cast<uint32_t*>(&p1);
        *reinterpret_cast<uint2*>(&PH[PCB_H + px * 80 + o0]) = pk2;
    }
    __syncthreads();   // B6

    // ---- mlp1 (relu) via MFMA: PCB -> H1 ----
    {
        f32x4 d = tile_gemm64(PH, PCB_H, w1, b1, wv >> 2, wv & 3, lane);
        #pragma unroll
        for (int r = 0; r < 4; ++r) d[r] = fmaxf(d[r], 0.0f);
        const int px = (wv & 3) * 16 + (lane & 15);
        const int o0 = (wv >> 2) * 16 + ((lane >> 4) << 2);
        __half2 p0 = __floats2half2_rn(d[0], d[1]);
        __half2 p1 = __floats2half2_rn(d[2], d[3]);
        uint2 pk2;
        pk2.x = *reinterpret_cast<uint32_t*>(&p0);
        pk2.y = *reinterpret_cast<uint32_t*>(&p1);
        *reinterpret_cast<uint2*>(&PH[H1_H + px * 80 + o0]) = pk2;
    }
    __syncthreads();   // B7

    // ---- mlp2 via MFMA + residual + NCHW store ----
    {
        f32x4 d = tile_gemm64(PH, H1_H, w2, b2, wv >> 2, wv & 3, lane);
        const int px = (wv & 3) * 16 + (lane & 15);
        const int o0 = (wv >> 2) * 16 + ((lane >> 4) << 2);
        #pragma unroll
        for (int r = 0; r < 4; ++r) {
            const int o = o0 + r;
            size_t idx = (((size_t)b * 64 + o) * 64 + y) * 64 + px;
            out[idx] = d[r] + x[idx];
        }
    }
}

extern "C" void kernel_launch(void* const* d_in, const int* in_sizes, int n_in,
                              void* d_out, int out_size, void* d_ws, size_t ws_size,
                              hipStream_t stream) {
    const float* x     = (const float*)d_in[0];
    const float* p_n   = (const float*)d_in[1];
    const float* dwf_w = (const float*)d_in[2];
    const float* dwf_b = (const float*)d_in[3];
    const float* pwf_w = (const float*)d_in[4];
    const float* pwf_b = (const float*)d_in[5];
    const float* dwc_w = (const float*)d_in[6];
    const float* dwc_b = (const float*)d_in[7];
    const float* pwc_w = (const float*)d_in[8];
    const float* pwc_b = (const float*)d_in[9];
    const float* dwm_w = (const float*)d_in[10];
    const float* dwm_b = (const float*)d_in[11];
    const float* pwm_w = (const float*)d_in[12];
    const float* pwm_b = (const float*)d_in[13];
    const float* pc_w  = (const float*)d_in[14];
    const float* pc_b  = (const float*)d_in[15];
    const float* w1    = (const float*)d_in[16];
    const float* b1    = (const float*)d_in[17];
    const float* w2    = (const float*)d_in[18];
    const float* b2    = (const float*)d_in[19];

    __half* xth = (__half*)d_ws;      // 2 MB NHWC fp16 copy of x
    float* outp = (float*)d_out;

    hipLaunchKernelGGL(transpose_half, dim3(BB * HH), dim3(256), 0, stream, x, xth);
    hipLaunchKernelGGL(crossd_main, dim3(BB * HH), dim3(1024), 0, stream,
                       xth, x, p_n,
                       dwf_w, dwf_b, pwf_w, pwf_b,
                       dwc_w, dwc_b, pwc_w, pwc_b,
                       dwm_w, dwm_b, pwm_w, pwm_b,
                       pc_w, pc_b, w1, b1, w2, b2, outp);
}

// Round 12
// 48.833 us; speedup vs baseline: 1.7215x; 1.0322x over previous
//
#include <hip/hip_runtime.h>
#include <hip/hip_fp16.h>
#include <cmath>

#define BB 4
#define HH 64
#define WW 64

// ---- LDS pool (per half-row block): 18377 words = 73.5 KB -> 2 blocks/CU ----
// word offsets
#define OFFW  9960      // [104][33] f32: ox rows 0..51, oy rows 52..103
#define SBW   13392     // [53][35] f32: scores
#define CMAP  15247     // [25][33] f32: per-pixel 5x5 cell weight map
#define FLBC  16072     // fallback counter
#define FLB   16073     // fallback list, 512 x uint2
#define POOLW 18377
// half-indexed bases
#define WIN_H 0         // [5][36 cols][68 stride] fp16 window (12240 halves)
#define TF_H  12240     // t_f [32 px][80] fp16
#define TC_H  14800
#define TM_H  17360     // end 19920 halves
#define AGG_H 34194     // agg [32][80] fp16 (words 17097..18377)
#define PCB_H 19920     // pc out [32][80] fp16, overlays OFFW (dead after coordpack)
#define H1_H  22480     // h1     [32][80] fp16, overlays OFFW

typedef _Float16 f16x8 __attribute__((ext_vector_type(8)));
typedef float    f32x4 __attribute__((ext_vector_type(4)));

// ---------------- NCHW -> NHWC fp16 transpose (LDS tiled) ----------------
__global__ __launch_bounds__(256) void transpose_half(const float* __restrict__ x,
                                                      __half* __restrict__ xth) {
    int bid = blockIdx.x;
    int b = bid >> 6, y = bid & 63;
    __shared__ float tile[64][65];
    const float* xp = x + ((size_t)b * 64 * HH + y) * WW;
    #pragma unroll
    for (int k = 0; k < 16; ++k) {
        int idx = threadIdx.x + (k << 8);
        int c = idx >> 6, w = idx & 63;
        tile[c][w] = xp[(size_t)c * HH * WW + w];
    }
    __syncthreads();
    __half* op = xth + ((size_t)(b * HH + y) * WW) * 64;
    #pragma unroll
    for (int k = 0; k < 16; ++k) {
        int idx = threadIdx.x + (k << 8);
        int w = idx >> 6, c = idx & 63;
        op[(size_t)w * 64 + c] = __float2half(tile[c][w]);
    }
}

// one 16x16 output tile per wave: D = W(64x64 f32 global) x act(PH [px][80] f16) + bias
__device__ inline f32x4 tile_gemm64(const __half* PH, int actH,
                                    const float* __restrict__ W,
                                    const float* __restrict__ Bv,
                                    int m_t, int n_t, int lane) {
    const int row = m_t * 16 + (lane & 15);
    const int kg  = (lane >> 4) * 8;
    const float* wr = W + row * 64 + kg;
    float4 wa0 = *reinterpret_cast<const float4*>(wr);
    float4 wa1 = *reinterpret_cast<const float4*>(wr + 4);
    float4 wb0 = *reinterpret_cast<const float4*>(wr + 32);
    float4 wb1 = *reinterpret_cast<const float4*>(wr + 36);
    f16x8 a0, a1;
    a0[0]=(_Float16)wa0.x; a0[1]=(_Float16)wa0.y; a0[2]=(_Float16)wa0.z; a0[3]=(_Float16)wa0.w;
    a0[4]=(_Float16)wa1.x; a0[5]=(_Float16)wa1.y; a0[6]=(_Float16)wa1.z; a0[7]=(_Float16)wa1.w;
    a1[0]=(_Float16)wb0.x; a1[1]=(_Float16)wb0.y; a1[2]=(_Float16)wb0.z; a1[3]=(_Float16)wb0.w;
    a1[4]=(_Float16)wb1.x; a1[5]=(_Float16)wb1.y; a1[6]=(_Float16)wb1.z; a1[7]=(_Float16)wb1.w;
    const int px = n_t * 16 + (lane & 15);
    f16x8 b0 = *reinterpret_cast<const f16x8*>(&PH[actH + px * 80 + kg]);
    f16x8 b1 = *reinterpret_cast<const f16x8*>(&PH[actH + px * 80 + 32 + kg]);
    f32x4 d;
    const int r0 = m_t * 16 + ((lane >> 4) << 2);
    #pragma unroll
    for (int r = 0; r < 4; ++r) d[r] = Bv[r0 + r];
    d = __builtin_amdgcn_mfma_f32_16x16x32_f16(a0, b0, d, 0, 0, 0);
    d = __builtin_amdgcn_mfma_f32_16x16x32_f16(a1, b1, d, 0, 0, 0);
    return d;
}

// ---------------- fused main: 1 block (8 waves, 512 thr) per HALF row; 2 blocks/CU ----------------
__global__ __launch_bounds__(512, 4) void crossd_main(
    const __half* __restrict__ xth, const float* __restrict__ x,
    const float* __restrict__ p_n,
    const float* __restrict__ dwf_w, const float* __restrict__ dwf_b,
    const float* __restrict__ pwf_w, const float* __restrict__ pwf_b,
    const float* __restrict__ dwc_w, const float* __restrict__ dwc_b,
    const float* __restrict__ pwc_w, const float* __restrict__ pwc_b,
    const float* __restrict__ dwm_w, const float* __restrict__ dwm_b,
    const float* __restrict__ pwm_w, const float* __restrict__ pwm_b,
    const float* __restrict__ pc_w, const float* __restrict__ pc_b,
    const float* __restrict__ w1, const float* __restrict__ b1,
    const float* __restrict__ w2, const float* __restrict__ b2,
    float* __restrict__ out)
{
    __shared__ float P[POOLW];
    uint32_t* PU = reinterpret_cast<uint32_t*>(P);
    __half*   PH = reinterpret_cast<__half*>(P);
    const int tid  = threadIdx.x;
    const int lane = tid & 63;
    const int wv   = __builtin_amdgcn_readfirstlane(tid >> 6);   // 0..7
    const int bid = blockIdx.x;                                  // 512 blocks
    const int xh = bid & 1, y = (bid >> 1) & 63, b = bid >> 7;
    const int x0 = xh << 5;                                      // half-row origin
    const int ry0 = min(max(y - 1, 0), 59);                      // window rows ry0..ry0+4
    const __half* xbh = xth + (size_t)b * (HH * WW * 64);
    const uint2* xb2 = reinterpret_cast<const uint2*>(xbh);

    // ---- phase 0: stage 5-row x 36-col fp16 window (stride 68) + zero CMAP/counter ----
    {
        for (int idx = tid; idx < 5 * 36 * 16; idx += 512) {
            int j = idx / 576;
            int rem = idx - j * 576;
            int col = rem >> 4, c4v = idx & 15;
            int gcol = min(max(x0 - 1 + col, 0), 63);
            *reinterpret_cast<uint2*>(&PH[(j * 36 + col) * 68 + c4v * 4]) =
                xb2[(((ry0 + j) << 6) + gcol) * 16 + c4v];
        }
        for (int i = tid; i < 25 * 33 + 1; i += 512) P[CMAP + i] = 0.0f;  // CMAP + FLBC
    }
    __syncthreads();   // B0

    // ---- depthwise 3x3 from window: wave = 4 px, lane = ch; fp16 t-buffers [32][80] ----
    {
        const int c = lane;
        float wf9[9], wc9[9], wm9[9];
        #pragma unroll
        for (int k9 = 0; k9 < 9; ++k9) {
            wf9[k9] = dwf_w[c * 9 + k9];
            wc9[k9] = dwc_w[c * 9 + k9];
            wm9[k9] = dwm_w[c * 9 + k9];
        }
        const float bf = dwf_b[c], bc = dwc_b[c], bm = dwm_b[c];
        #pragma unroll
        for (int i = 0; i < 4; ++i) {
            const int pl = wv * 4 + i;          // local px
            const int pg = x0 + pl;             // global px
            float af = bf, ac = bc, am = bm;
            #pragma unroll
            for (int dy = 0; dy < 3; ++dy) {
                int yy = y + dy - 1;
                if (yy < 0 || yy >= HH) continue;
                int j = yy - ry0;
                #pragma unroll
                for (int dx = 0; dx < 3; ++dx) {
                    int xx = pg + dx - 1;
                    if (xx < 0 || xx >= WW) continue;
                    int co = xx - x0 + 1;       // window col 0..33
                    float v = __half2float(PH[(j * 36 + co) * 68 + c]);
                    int k = dy * 3 + dx;
                    af = fmaf(v, wf9[k], af);
                    ac = fmaf(v, wc9[k], ac);
                    am = fmaf(v, wm9[k], am);
                }
            }
            PH[TF_H + pl * 80 + c] = __float2half(af);
            PH[TC_H + pl * 80 + c] = __float2half(ac);
            PH[TM_H + pl * 80 + c] = __float2half(am);
        }
    }
    __syncthreads();   // B1

    // ---- fused f+c+m pointwise via MFMA: 11 m-tiles x 2 n-tiles over 8 waves ----
    {
        const int n_t = wv & 1;
        const int g   = wv >> 1;
        #pragma unroll
        for (int t = 0; t < 3; ++t) {
            const int m_t = g + t * 4;
            if (m_t < 11) {
                const float *Wb, *Bvb; int rows, actH, r0b, br;
                if (m_t < 2)      { Wb=pwf_w; Bvb=pwf_b; rows=32; actH=TF_H; r0b=m_t*16;     br=0; }
                else if (m_t < 7) { Wb=pwc_w; Bvb=pwc_b; rows=72; actH=TC_H; r0b=(m_t-2)*16; br=1; }
                else              { Wb=pwm_w; Bvb=pwm_b; rows=53; actH=TM_H; r0b=(m_t-7)*16; br=2; }
                const int rl  = min(r0b + (lane & 15), rows - 1);
                const int kg  = (lane >> 4) * 8;
                const float* wr = Wb + rl * 64 + kg;
                float4 wa0 = *reinterpret_cast<const float4*>(wr);
                float4 wa1 = *reinterpret_cast<const float4*>(wr + 4);
                float4 wb0 = *reinterpret_cast<const float4*>(wr + 32);
                float4 wb1 = *reinterpret_cast<const float4*>(wr + 36);
                f16x8 a0, a1;
                a0[0]=(_Float16)wa0.x; a0[1]=(_Float16)wa0.y; a0[2]=(_Float16)wa0.z; a0[3]=(_Float16)wa0.w;
                a0[4]=(_Float16)wa1.x; a0[5]=(_Float16)wa1.y; a0[6]=(_Float16)wa1.z; a0[7]=(_Float16)wa1.w;
                a1[0]=(_Float16)wb0.x; a1[1]=(_Float16)wb0.y; a1[2]=(_Float16)wb0.z; a1[3]=(_Float16)wb0.w;
                a1[4]=(_Float16)wb1.x; a1[5]=(_Float16)wb1.y; a1[6]=(_Float16)wb1.z; a1[7]=(_Float16)wb1.w;
                const int px = n_t * 16 + (lane & 15);
                f16x8 b0 = *reinterpret_cast<const f16x8*>(&PH[actH + px * 80 + kg]);
                f16x8 b1 = *reinterpret_cast<const f16x8*>(&PH[actH + px * 80 + 32 + kg]);
                f32x4 d;
                const int rr0 = r0b + ((lane >> 4) << 2);
                #pragma unroll
                for (int r = 0; r < 4; ++r) d[r] = Bvb[min(rr0 + r, rows - 1)];
                d = __builtin_amdgcn_mfma_f32_16x16x32_f16(a0, b0, d, 0, 0, 0);
                d = __builtin_amdgcn_mfma_f32_16x16x32_f16(a1, b1, d, 0, 0, 0);
                #pragma unroll
                for (int r = 0; r < 4; ++r) {
                    const int rb = rr0 + r;
                    if (rb < rows) {
                        const float v = d[r];
                        if (br == 2)      P[SBW + rb * 35 + px] = v;
                        else {
                            int og = (br == 0) ? rb : 32 + rb;
                            P[OFFW + og * 33 + px] = v;
                        }
                    }
                }
            }
        }
    }
    __syncthreads();   // B2

    // ---- fused gated-softmax + coordpack (cell-map accumulate): wave owns 4 px ----
    #pragma unroll 1
    for (int i = 0; i < 4; ++i) {
        const int pl = wv * 4 + i;
        const float sp = P[SBW + 52 * 35 + pl];
        float z = -1e30f;
        if (lane < 52) {
            float s  = P[SBW + lane * 35 + pl];
            float sg = 1.0f / (1.0f + __expf(-(s - sp) * 10.0f));
            z = s + __logf(sg + 1e-10f);
        }
        float mx = z;
        #pragma unroll
        for (int d = 32; d >= 1; d >>= 1) mx = fmaxf(mx, __shfl_xor(mx, d));
        float e = (lane < 52) ? __expf(z - mx) : 0.0f;
        float sm = e;
        #pragma unroll
        for (int d = 32; d >= 1; d >>= 1) sm += __shfl_xor(sm, d);
        if (lane < 52) {
            const float mo = e / sm;
            const int pg = x0 + pl;
            float sx = (float)pg + p_n[lane]      + P[OFFW + lane * 33 + pl];
            float sy = (float)y  + p_n[52 + lane] + P[OFFW + (52 + lane) * 33 + pl];
            float x0f = floorf(sx), y0f = floorf(sy);
            float wx1 = sx - x0f, wy1 = sy - y0f;
            float wx0 = 1.0f - wx1, wy0 = 1.0f - wy1;
            int xi = (int)x0f, yi = (int)y0f;
            bool vx0 = (xi >= 0)  & (xi <= 63);
            bool vx1 = (xi >= -1) & (xi <= 62);
            bool vy0 = (yi >= 0)  & (yi <= 63);
            bool vy1 = (yi >= -1) & (yi <= 62);
            float m00 = (vy0 & vx0) ? mo * wy0 * wx0 : 0.0f;
            float m01 = (vy0 & vx1) ? mo * wy0 * wx1 : 0.0f;
            float m10 = (vy1 & vx0) ? mo * wy1 * wx0 : 0.0f;
            float m11 = (vy1 & vx1) ? mo * wy1 * wx1 : 0.0f;
            const int i0 = xi - pg + 1, j0 = yi - ry0;
            #define PUSH(m, jj, ii, gx, gy) \
                if (m != 0.0f) { \
                    if ((jj) >= 0 && (jj) <= 4 && (ii) >= 0 && (ii) <= 4) { \
                        atomicAdd(&P[CMAP + ((jj) * 5 + (ii)) * 33 + pl], m); \
                    } else { \
                        uint32_t a = (uint32_t)((gy) * 64 + (gx)); \
                        uint32_t sl = atomicAdd(&PU[FLBC], 1u); \
                        if (sl < 512u) { \
                            PU[FLB + sl * 2]     = a | ((uint32_t)pl << 16); \
                            PU[FLB + sl * 2 + 1] = __float_as_uint(m); \
                        } \
                    } \
                }
            PUSH(m00, j0,     i0,     xi,     yi);
            PUSH(m01, j0,     i0 + 1, xi + 1, yi);
            PUSH(m10, j0 + 1, i0,     xi,     yi + 1);
            PUSH(m11, j0 + 1, i0 + 1, xi + 1, yi + 1);
            #undef PUSH
        }
    }
    __syncthreads();   // B3

    // ---- 25-cell gather: W[cell][px] broadcast x window b64; agg -> fp16 [32][80] ----
    {
        const int sub = lane >> 4;
        const int c4  = lane & 15;
        const int spx = wv * 4 + sub;        // local px
        const int spg = x0 + spx;            // global px
        int co[5];
        #pragma unroll
        for (int i = 0; i < 5; ++i) co[i] = min(max(spg - 1 + i, 0), 63) - x0 + 1;
        float4 agg = make_float4(0.f, 0.f, 0.f, 0.f);
        #pragma unroll
        for (int j = 0; j < 5; ++j) {
            #pragma unroll
            for (int i = 0; i < 5; ++i) {
                float w = P[CMAP + (j * 5 + i) * 33 + spx];
                uint2 u = *reinterpret_cast<const uint2*>(&PH[(j * 36 + co[i]) * 68 + c4 * 4]);
                __half2 hlo = *reinterpret_cast<const __half2*>(&u.x);
                __half2 hhi = *reinterpret_cast<const __half2*>(&u.y);
                float2 flo = __half22float2(hlo), fhi = __half22float2(hhi);
                agg.x = fmaf(w, flo.x, agg.x); agg.y = fmaf(w, flo.y, agg.y);
                agg.z = fmaf(w, fhi.x, agg.z); agg.w = fmaf(w, fhi.y, agg.w);
            }
        }
        // rare out-of-neighborhood fallback (normally count == 0)
        const int cnt = min((int)PU[FLBC], 512);
        for (int e = 0; e < cnt; ++e) {
            uint32_t ea = PU[FLB + e * 2];
            float m = __uint_as_float(PU[FLB + e * 2 + 1]);
            if ((int)(ea >> 16) == spx) {
                uint2 u = xb2[(ea & 0xFFFFu) * 16 + c4];
                __half2 hlo = *reinterpret_cast<const __half2*>(&u.x);
                __half2 hhi = *reinterpret_cast<const __half2*>(&u.y);
                float2 flo = __half22float2(hlo), fhi = __half22float2(hhi);
                agg.x = fmaf(m, flo.x, agg.x); agg.y = fmaf(m, flo.y, agg.y);
                agg.z = fmaf(m, fhi.x, agg.z); agg.w = fmaf(m, fhi.y, agg.w);
            }
        }
        __half2 p0 = __floats2half2_rn(agg.x, agg.y);
        __half2 p1 = __floats2half2_rn(agg.z, agg.w);
        uint2 pk2;
        pk2.x = *reinterpret_cast<uint32_t*>(&p0);
        pk2.y = *reinterpret_cast<uint32_t*>(&p1);
        *reinterpret_cast<uint2*>(&PH[AGG_H + spx * 80 + c4 * 4]) = pk2;
    }
    __syncthreads();   // B4

    // ---- pc 1x1 via MFMA: AGG -> PCB ----
    {
        f32x4 d = tile_gemm64(PH, AGG_H, pc_w, pc_b, wv >> 1, wv & 1, lane);
        const int px = (wv & 1) * 16 + (lane & 15);
        const int o0 = (wv >> 1) * 16 + ((lane >> 4) << 2);
        __half2 p0 = __floats2half2_rn(d[0], d[1]);
        __half2 p1 = __floats2half2_rn(d[2], d[3]);
        uint2 pk2;
        pk2.x = *reinterpret_cast<uint32_t*>(&p0);
        pk2.y = *reinterpret_cast<uint32_t*>(&p1);
        *reinterpret_cast<uint2*>(&PH[PCB_H + px * 80 + o0]) = pk2;
    }
    __syncthreads();   // B5

    // ---- mlp1 (relu) via MFMA: PCB -> H1 ----
    {
        f32x4 d = tile_gemm64(PH, PCB_H, w1, b1, wv >> 1, wv & 1, lane);
        #pragma unroll
        for (int r = 0; r < 4; ++r) d[r] = fmaxf(d[r], 0.0f);
        const int px = (wv & 1) * 16 + (lane & 15);
        const int o0 = (wv >> 1) * 16 + ((lane >> 4) << 2);
        __half2 p0 = __floats2half2_rn(d[0], d[1]);
        __half2 p1 = __floats2half2_rn(d[2], d[3]);
        uint2 pk2;
        pk2.x = *reinterpret_cast<uint32_t*>(&p0);
        pk2.y = *reinterpret_cast<uint32_t*>(&p1);
        *reinterpret_cast<uint2*>(&PH[H1_H + px * 80 + o0]) = pk2;
    }
    __syncthreads();   // B6

    // ---- mlp2 via MFMA + residual + NCHW store ----
    {
        f32x4 d = tile_gemm64(PH, H1_H, w2, b2, wv >> 1, wv & 1, lane);
        const int px = (wv & 1) * 16 + (lane & 15);
        const int o0 = (wv >> 1) * 16 + ((lane >> 4) << 2);
        #pragma unroll
        for (int r = 0; r < 4; ++r) {
            const int o = o0 + r;
            size_t idx = (((size_t)b * 64 + o) * 64 + y) * 64 + x0 + px;
            out[idx] = d[r] + x[idx];
        }
    }
}

extern "C" void kernel_launch(void* const* d_in, const int* in_sizes, int n_in,
                              void* d_out, int out_size, void* d_ws, size_t ws_size,
                              hipStream_t stream) {
    const float* x     = (const float*)d_in[0];
    const float* p_n   = (const float*)d_in[1];
    const float* dwf_w = (const float*)d_in[2];
    const float* dwf_b = (const float*)d_in[3];
    const float* pwf_w = (const float*)d_in[4];
    const float* pwf_b = (const float*)d_in[5];
    const float* dwc_w = (const float*)d_in[6];
    const float* dwc_b = (const float*)d_in[7];
    const float* pwc_w = (const float*)d_in[8];
    const float* pwc_b = (const float*)d_in[9];
    const float* dwm_w = (const float*)d_in[10];
    const float* dwm_b = (const float*)d_in[11];
    const float* pwm_w = (const float*)d_in[12];
    const float* pwm_b = (const float*)d_in[13];
    const float* pc_w  = (const float*)d_in[14];
    const float* pc_b  = (const float*)d_in[15];
    const float* w1    = (const float*)d_in[16];
    const float* b1    = (const float*)d_in[17];
    const float* w2    = (const float*)d_in[18];
    const float* b2    = (const float*)d_in[19];

    __half* xth = (__half*)d_ws;      // 2 MB NHWC fp16 copy of x
    float* outp = (float*)d_out;

    hipLaunchKernelGGL(transpose_half, dim3(BB * HH), dim3(256), 0, stream, x, xth);
    hipLaunchKernelGGL(crossd_main, dim3(BB * HH * 2), dim3(512), 0, stream,
                       xth, x, p_n,
                       dwf_w, dwf_b, pwf_w, pwf_b,
                       dwc_w, dwc_b, pwc_w, pwc_b,
                       dwm_w, dwm_b, pwm_w, pwm_b,
                       pc_w, pc_b, w1, b1, w2, b2, outp);
}

// Round 13
// 46.051 us; speedup vs baseline: 1.8255x; 1.0604x over previous
//
#include <hip/hip_runtime.h>
#include <hip/hip_fp16.h>
#include <cmath>

#define BB 4
#define HH 64
#define WW 64

// ---- LDS pool (per half-row block): 18377 words = 73.5 KB -> 2 blocks/CU ----
// word offsets
#define OFFW  9960      // [104][33] f32: ox rows 0..51, oy rows 52..103
#define SBW   13392     // [53][35] f32: scores
#define CMAP  15247     // [25][33] f32: per-pixel 5x5 cell weight map
#define FLBC  16072     // fallback counter
#define FLB   16073     // fallback list, 512 x uint2
#define POOLW 18377
// half-indexed bases
#define WIN_H 0         // [5][36 cols][68 stride] fp16 window (12240 halves)
#define TF_H  12240     // t_f [32 px][80] fp16
#define TC_H  14800
#define TM_H  17360     // end 19920 halves
#define AGG_H 34194     // agg [32][80] fp16 (words 17097..18377)
#define PCB_H 19920     // pc out [32][80] fp16, overlays OFFW (dead after coordpack)
#define H1_H  22480     // h1     [32][80] fp16, overlays OFFW

typedef _Float16 f16x8 __attribute__((ext_vector_type(8)));
typedef float    f32x4 __attribute__((ext_vector_type(4)));

// one 16x16 output tile per wave: D = W(64x64 f32 global) x act(PH [px][80] f16) + bias
__device__ inline f32x4 tile_gemm64(const __half* PH, int actH,
                                    const float* __restrict__ W,
                                    const float* __restrict__ Bv,
                                    int m_t, int n_t, int lane) {
    const int row = m_t * 16 + (lane & 15);
    const int kg  = (lane >> 4) * 8;
    const float* wr = W + row * 64 + kg;
    float4 wa0 = *reinterpret_cast<const float4*>(wr);
    float4 wa1 = *reinterpret_cast<const float4*>(wr + 4);
    float4 wb0 = *reinterpret_cast<const float4*>(wr + 32);
    float4 wb1 = *reinterpret_cast<const float4*>(wr + 36);
    f16x8 a0, a1;
    a0[0]=(_Float16)wa0.x; a0[1]=(_Float16)wa0.y; a0[2]=(_Float16)wa0.z; a0[3]=(_Float16)wa0.w;
    a0[4]=(_Float16)wa1.x; a0[5]=(_Float16)wa1.y; a0[6]=(_Float16)wa1.z; a0[7]=(_Float16)wa1.w;
    a1[0]=(_Float16)wb0.x; a1[1]=(_Float16)wb0.y; a1[2]=(_Float16)wb0.z; a1[3]=(_Float16)wb0.w;
    a1[4]=(_Float16)wb1.x; a1[5]=(_Float16)wb1.y; a1[6]=(_Float16)wb1.z; a1[7]=(_Float16)wb1.w;
    const int px = n_t * 16 + (lane & 15);
    f16x8 b0 = *reinterpret_cast<const f16x8*>(&PH[actH + px * 80 + kg]);
    f16x8 b1 = *reinterpret_cast<const f16x8*>(&PH[actH + px * 80 + 32 + kg]);
    f32x4 d;
    const int r0 = m_t * 16 + ((lane >> 4) << 2);
    #pragma unroll
    for (int r = 0; r < 4; ++r) d[r] = Bv[r0 + r];
    d = __builtin_amdgcn_mfma_f32_16x16x32_f16(a0, b0, d, 0, 0, 0);
    d = __builtin_amdgcn_mfma_f32_16x16x32_f16(a1, b1, d, 0, 0, 0);
    return d;
}

// ---------------- fused main: 1 block (8 waves, 512 thr) per HALF row; 2 blocks/CU ----------------
__global__ __launch_bounds__(512, 4) void crossd_main(
    const float* __restrict__ x,
    const float* __restrict__ p_n,
    const float* __restrict__ dwf_w, const float* __restrict__ dwf_b,
    const float* __restrict__ pwf_w, const float* __restrict__ pwf_b,
    const float* __restrict__ dwc_w, const float* __restrict__ dwc_b,
    const float* __restrict__ pwc_w, const float* __restrict__ pwc_b,
    const float* __restrict__ dwm_w, const float* __restrict__ dwm_b,
    const float* __restrict__ pwm_w, const float* __restrict__ pwm_b,
    const float* __restrict__ pc_w, const float* __restrict__ pc_b,
    const float* __restrict__ w1, const float* __restrict__ b1,
    const float* __restrict__ w2, const float* __restrict__ b2,
    float* __restrict__ out)
{
    __shared__ float P[POOLW];
    uint32_t* PU = reinterpret_cast<uint32_t*>(P);
    __half*   PH = reinterpret_cast<__half*>(P);
    const int tid  = threadIdx.x;
    const int lane = tid & 63;
    const int wv   = __builtin_amdgcn_readfirstlane(tid >> 6);   // 0..7
    const int bid = blockIdx.x;                                  // 512 blocks
    const int xh = bid & 1, y = (bid >> 1) & 63, b = bid >> 7;
    const int x0 = xh << 5;                                      // half-row origin
    const int ry0 = min(max(y - 1, 0), 59);                      // window rows ry0..ry0+4
    const float* xb = x + (size_t)b * (64 * HH * WW);            // NCHW batch base

    // ---- phase 0: stage 5-row x 36-col fp16 window DIRECTLY from NCHW x ----
    {
        // idx = (j, c, col), col fastest -> coalesced 144 B row segments per (j,c)
        for (int idx = tid; idx < 5 * 64 * 36; idx += 512) {
            int j   = idx / (64 * 36);
            int rem = idx - j * (64 * 36);
            int c   = rem / 36;
            int col = rem - c * 36;
            int gcol = min(max(x0 - 1 + col, 0), 63);
            float v = xb[((size_t)c * HH + (ry0 + j)) * WW + gcol];
            PH[(j * 36 + col) * 68 + c] = __float2half(v);
        }
        for (int i = tid; i < 25 * 33 + 1; i += 512) P[CMAP + i] = 0.0f;  // CMAP + FLBC
    }
    __syncthreads();   // B0

    // ---- depthwise 3x3 from window: wave = 4 px, lane = ch; fp16 t-buffers [32][80] ----
    {
        const int c = lane;
        float wf9[9], wc9[9], wm9[9];
        #pragma unroll
        for (int k9 = 0; k9 < 9; ++k9) {
            wf9[k9] = dwf_w[c * 9 + k9];
            wc9[k9] = dwc_w[c * 9 + k9];
            wm9[k9] = dwm_w[c * 9 + k9];
        }
        const float bf = dwf_b[c], bc = dwc_b[c], bm = dwm_b[c];
        #pragma unroll
        for (int i = 0; i < 4; ++i) {
            const int pl = wv * 4 + i;          // local px
            const int pg = x0 + pl;             // global px
            float af = bf, ac = bc, am = bm;
            #pragma unroll
            for (int dy = 0; dy < 3; ++dy) {
                int yy = y + dy - 1;
                if (yy < 0 || yy >= HH) continue;
                int j = yy - ry0;
                #pragma unroll
                for (int dx = 0; dx < 3; ++dx) {
                    int xx = pg + dx - 1;
                    if (xx < 0 || xx >= WW) continue;
                    int co = xx - x0 + 1;       // window col 0..33
                    float v = __half2float(PH[(j * 36 + co) * 68 + c]);
                    int k = dy * 3 + dx;
                    af = fmaf(v, wf9[k], af);
                    ac = fmaf(v, wc9[k], ac);
                    am = fmaf(v, wm9[k], am);
                }
            }
            PH[TF_H + pl * 80 + c] = __float2half(af);
            PH[TC_H + pl * 80 + c] = __float2half(ac);
            PH[TM_H + pl * 80 + c] = __float2half(am);
        }
    }
    __syncthreads();   // B1

    // ---- fused f+c+m pointwise via MFMA: 11 m-tiles x 2 n-tiles over 8 waves ----
    {
        const int n_t = wv & 1;
        const int g   = wv >> 1;
        #pragma unroll
        for (int t = 0; t < 3; ++t) {
            const int m_t = g + t * 4;
            if (m_t < 11) {
                const float *Wb, *Bvb; int rows, actH, r0b, br;
                if (m_t < 2)      { Wb=pwf_w; Bvb=pwf_b; rows=32; actH=TF_H; r0b=m_t*16;     br=0; }
                else if (m_t < 7) { Wb=pwc_w; Bvb=pwc_b; rows=72; actH=TC_H; r0b=(m_t-2)*16; br=1; }
                else              { Wb=pwm_w; Bvb=pwm_b; rows=53; actH=TM_H; r0b=(m_t-7)*16; br=2; }
                const int rl  = min(r0b + (lane & 15), rows - 1);
                const int kg  = (lane >> 4) * 8;
                const float* wr = Wb + rl * 64 + kg;
                float4 wa0 = *reinterpret_cast<const float4*>(wr);
                float4 wa1 = *reinterpret_cast<const float4*>(wr + 4);
                float4 wb0 = *reinterpret_cast<const float4*>(wr + 32);
                float4 wb1 = *reinterpret_cast<const float4*>(wr + 36);
                f16x8 a0, a1;
                a0[0]=(_Float16)wa0.x; a0[1]=(_Float16)wa0.y; a0[2]=(_Float16)wa0.z; a0[3]=(_Float16)wa0.w;
                a0[4]=(_Float16)wa1.x; a0[5]=(_Float16)wa1.y; a0[6]=(_Float16)wa1.z; a0[7]=(_Float16)wa1.w;
                a1[0]=(_Float16)wb0.x; a1[1]=(_Float16)wb0.y; a1[2]=(_Float16)wb0.z; a1[3]=(_Float16)wb0.w;
                a1[4]=(_Float16)wb1.x; a1[5]=(_Float16)wb1.y; a1[6]=(_Float16)wb1.z; a1[7]=(_Float16)wb1.w;
                const int px = n_t * 16 + (lane & 15);
                f16x8 b0 = *reinterpret_cast<const f16x8*>(&PH[actH + px * 80 + kg]);
                f16x8 b1 = *reinterpret_cast<const f16x8*>(&PH[actH + px * 80 + 32 + kg]);
                f32x4 d;
                const int rr0 = r0b + ((lane >> 4) << 2);
                #pragma unroll
                for (int r = 0; r < 4; ++r) d[r] = Bvb[min(rr0 + r, rows - 1)];
                d = __builtin_amdgcn_mfma_f32_16x16x32_f16(a0, b0, d, 0, 0, 0);
                d = __builtin_amdgcn_mfma_f32_16x16x32_f16(a1, b1, d, 0, 0, 0);
                #pragma unroll
                for (int r = 0; r < 4; ++r) {
                    const int rb = rr0 + r;
                    if (rb < rows) {
                        const float v = d[r];
                        if (br == 2)      P[SBW + rb * 35 + px] = v;
                        else {
                            int og = (br == 0) ? rb : 32 + rb;
                            P[OFFW + og * 33 + px] = v;
                        }
                    }
                }
            }
        }
    }
    __syncthreads();   // B2

    // ---- fused gated-softmax + coordpack (cell-map accumulate): wave owns 4 px ----
    #pragma unroll 1
    for (int i = 0; i < 4; ++i) {
        const int pl = wv * 4 + i;
        const float sp = P[SBW + 52 * 35 + pl];
        float z = -1e30f;
        if (lane < 52) {
            float s  = P[SBW + lane * 35 + pl];
            float sg = 1.0f / (1.0f + __expf(-(s - sp) * 10.0f));
            z = s + __logf(sg + 1e-10f);
        }
        float mx = z;
        #pragma unroll
        for (int d = 32; d >= 1; d >>= 1) mx = fmaxf(mx, __shfl_xor(mx, d));
        float e = (lane < 52) ? __expf(z - mx) : 0.0f;
        float sm = e;
        #pragma unroll
        for (int d = 32; d >= 1; d >>= 1) sm += __shfl_xor(sm, d);
        if (lane < 52) {
            const float mo = e / sm;
            const int pg = x0 + pl;
            float sx = (float)pg + p_n[lane]      + P[OFFW + lane * 33 + pl];
            float sy = (float)y  + p_n[52 + lane] + P[OFFW + (52 + lane) * 33 + pl];
            float x0f = floorf(sx), y0f = floorf(sy);
            float wx1 = sx - x0f, wy1 = sy - y0f;
            float wx0 = 1.0f - wx1, wy0 = 1.0f - wy1;
            int xi = (int)x0f, yi = (int)y0f;
            bool vx0 = (xi >= 0)  & (xi <= 63);
            bool vx1 = (xi >= -1) & (xi <= 62);
            bool vy0 = (yi >= 0)  & (yi <= 63);
            bool vy1 = (yi >= -1) & (yi <= 62);
            float m00 = (vy0 & vx0) ? mo * wy0 * wx0 : 0.0f;
            float m01 = (vy0 & vx1) ? mo * wy0 * wx1 : 0.0f;
            float m10 = (vy1 & vx0) ? mo * wy1 * wx0 : 0.0f;
            float m11 = (vy1 & vx1) ? mo * wy1 * wx1 : 0.0f;
            const int i0 = xi - pg + 1, j0 = yi - ry0;
            #define PUSH(m, jj, ii, gx, gy) \
                if (m != 0.0f) { \
                    if ((jj) >= 0 && (jj) <= 4 && (ii) >= 0 && (ii) <= 4) { \
                        atomicAdd(&P[CMAP + ((jj) * 5 + (ii)) * 33 + pl], m); \
                    } else { \
                        uint32_t a = (uint32_t)((gy) * 64 + (gx)); \
                        uint32_t sl = atomicAdd(&PU[FLBC], 1u); \
                        if (sl < 512u) { \
                            PU[FLB + sl * 2]     = a | ((uint32_t)pl << 16); \
                            PU[FLB + sl * 2 + 1] = __float_as_uint(m); \
                        } \
                    } \
                }
            PUSH(m00, j0,     i0,     xi,     yi);
            PUSH(m01, j0,     i0 + 1, xi + 1, yi);
            PUSH(m10, j0 + 1, i0,     xi,     yi + 1);
            PUSH(m11, j0 + 1, i0 + 1, xi + 1, yi + 1);
            #undef PUSH
        }
    }
    __syncthreads();   // B3

    // ---- 25-cell gather: W[cell][px] broadcast x window b64; agg -> fp16 [32][80] ----
    {
        const int sub = lane >> 4;
        const int c4  = lane & 15;
        const int spx = wv * 4 + sub;        // local px
        const int spg = x0 + spx;            // global px
        int co[5];
        #pragma unroll
        for (int i = 0; i < 5; ++i) co[i] = min(max(spg - 1 + i, 0), 63) - x0 + 1;
        float4 agg = make_float4(0.f, 0.f, 0.f, 0.f);
        #pragma unroll
        for (int j = 0; j < 5; ++j) {
            #pragma unroll
            for (int i = 0; i < 5; ++i) {
                float w = P[CMAP + (j * 5 + i) * 33 + spx];
                uint2 u = *reinterpret_cast<const uint2*>(&PH[(j * 36 + co[i]) * 68 + c4 * 4]);
                __half2 hlo = *reinterpret_cast<const __half2*>(&u.x);
                __half2 hhi = *reinterpret_cast<const __half2*>(&u.y);
                float2 flo = __half22float2(hlo), fhi = __half22float2(hhi);
                agg.x = fmaf(w, flo.x, agg.x); agg.y = fmaf(w, flo.y, agg.y);
                agg.z = fmaf(w, fhi.x, agg.z); agg.w = fmaf(w, fhi.y, agg.w);
            }
        }
        // rare out-of-neighborhood fallback (normally count == 0); NCHW scalar reads
        const int cnt = min((int)PU[FLBC], 512);
        for (int e = 0; e < cnt; ++e) {
            uint32_t ea = PU[FLB + e * 2];
            float m = __uint_as_float(PU[FLB + e * 2 + 1]);
            if ((int)(ea >> 16) == spx) {
                int gy = (int)((ea & 0xFFFFu) >> 6), gx = (int)(ea & 63u);
                float v0 = xb[((size_t)(c4 * 4 + 0) * HH + gy) * WW + gx];
                float v1 = xb[((size_t)(c4 * 4 + 1) * HH + gy) * WW + gx];
                float v2 = xb[((size_t)(c4 * 4 + 2) * HH + gy) * WW + gx];
                float v3 = xb[((size_t)(c4 * 4 + 3) * HH + gy) * WW + gx];
                agg.x = fmaf(m, v0, agg.x); agg.y = fmaf(m, v1, agg.y);
                agg.z = fmaf(m, v2, agg.z); agg.w = fmaf(m, v3, agg.w);
            }
        }
        __half2 p0 = __floats2half2_rn(agg.x, agg.y);
        __half2 p1 = __floats2half2_rn(agg.z, agg.w);
        uint2 pk2;
        pk2.x = *reinterpret_cast<uint32_t*>(&p0);
        pk2.y = *reinterpret_cast<uint32_t*>(&p1);
        *reinterpret_cast<uint2*>(&PH[AGG_H + spx * 80 + c4 * 4]) = pk2;
    }
    __syncthreads();   // B4

    // ---- pc 1x1 via MFMA: AGG -> PCB ----
    {
        f32x4 d = tile_gemm64(PH, AGG_H, pc_w, pc_b, wv >> 1, wv & 1, lane);
        const int px = (wv & 1) * 16 + (lane & 15);
        const int o0 = (wv >> 1) * 16 + ((lane >> 4) << 2);
        __half2 p0 = __floats2half2_rn(d[0], d[1]);
        __half2 p1 = __floats2half2_rn(d[2], d[3]);
        uint2 pk2;
        pk2.x = *reinterpret_cast<uint32_t*>(&p0);
        pk2.y = *reinterpret_cast<uint32_t*>(&p1);
        *reinterpret_cast<uint2*>(&PH[PCB_H + px * 80 + o0]) = pk2;
    }
    __syncthreads();   // B5

    // ---- mlp1 (relu) via MFMA: PCB -> H1 ----
    {
        f32x4 d = tile_gemm64(PH, PCB_H, w1, b1, wv >> 1, wv & 1, lane);
        #pragma unroll
        for (int r = 0; r < 4; ++r) d[r] = fmaxf(d[r], 0.0f);
        const int px = (wv & 1) * 16 + (lane & 15);
        const int o0 = (wv >> 1) * 16 + ((lane >> 4) << 2);
        __half2 p0 = __floats2half2_rn(d[0], d[1]);
        __half2 p1 = __floats2half2_rn(d[2], d[3]);
        uint2 pk2;
        pk2.x = *reinterpret_cast<uint32_t*>(&p0);
        pk2.y = *reinterpret_cast<uint32_t*>(&p1);
        *reinterpret_cast<uint2*>(&PH[H1_H + px * 80 + o0]) = pk2;
    }
    __syncthreads();   // B6

    // ---- mlp2 via MFMA + residual + NCHW store ----
    {
        f32x4 d = tile_gemm64(PH, H1_H, w2, b2, wv >> 1, wv & 1, lane);
        const int px = (wv & 1) * 16 + (lane & 15);
        const int o0 = (wv >> 1) * 16 + ((lane >> 4) << 2);
        #pragma unroll
        for (int r = 0; r < 4; ++r) {
            const int o = o0 + r;
            size_t idx = (((size_t)b * 64 + o) * 64 + y) * 64 + x0 + px;
            out[idx] = d[r] + x[idx];
        }
    }
}

extern "C" void kernel_launch(void* const* d_in, const int* in_sizes, int n_in,
                              void* d_out, int out_size, void* d_ws, size_t ws_size,
                              hipStream_t stream) {
    const float* x     = (const float*)d_in[0];
    const float* p_n   = (const float*)d_in[1];
    const float* dwf_w = (const float*)d_in[2];
    const float* dwf_b = (const float*)d_in[3];
    const float* pwf_w = (const float*)d_in[4];
    const float* pwf_b = (const float*)d_in[5];
    const float* dwc_w = (const float*)d_in[6];
    const float* dwc_b = (const float*)d_in[7];
    const float* pwc_w = (const float*)d_in[8];
    const float* pwc_b = (const float*)d_in[9];
    const float* dwm_w = (const float*)d_in[10];
    const float* dwm_b = (const float*)d_in[11];
    const float* pwm_w = (const float*)d_in[12];
    const float* pwm_b = (const float*)d_in[13];
    const float* pc_w  = (const float*)d_in[14];
    const float* pc_b  = (const float*)d_in[15];
    const float* w1    = (const float*)d_in[16];
    const float* b1    = (const float*)d_in[17];
    const float* w2    = (const float*)d_in[18];
    const float* b2    = (const float*)d_in[19];

    float* outp = (float*)d_out;

    hipLaunchKernelGGL(crossd_main, dim3(BB * HH * 2), dim3(512), 0, stream,
                       x, p_n,
                       dwf_w, dwf_b, pwf_w, pwf_b,
                       dwc_w, dwc_b, pwc_w, pwc_b,
                       dwm_w, dwm_b, pwm_w, pwm_b,
                       pc_w, pc_b, w1, b1, w2, b2, outp);
}